// Round 1
// baseline (1082.467 us; speedup 1.0000x reference)
//
#include <hip/hip_runtime.h>
#include <cstdint>
#include <math.h>

#define B2v 4
#define Cc  128
#define Hh  64
#define Ww  256
#define Gg  8
#define Pp  4
#define Dd  16
#define HW  (Hh*Ww)      // 16384
#define CHW (Cc*HW)      // 2097152

// ---------------------------------------------------------------------------
// Kernel 1: value = wv @ ctx + bv ; nfeat = wn @ geo + bn   (planar outputs)
// block = 256 threads, grid = (W/64, H, B2)
// ---------------------------------------------------------------------------
__global__ __launch_bounds__(256) void kv_kernel(
    const float* __restrict__ fl, const float* __restrict__ fr,
    const float* __restrict__ nl, const float* __restrict__ nr,
    const float* __restrict__ wv, const float* __restrict__ bv,
    const float* __restrict__ wn, const float* __restrict__ bn,
    float* __restrict__ value_pl, float* __restrict__ nfeat_pl)
{
    __shared__ float sc[Cc][64];
    __shared__ float sg[3][64];
    const int t   = threadIdx.x;
    const int wl  = t & 63;
    const int quad = t >> 6;
    const int wt = blockIdx.x, h = blockIdx.y, b = blockIdx.z;
    const int w0 = wt * 64;

    // ctx = concat([feat_right, feat_left]); geo = concat([normal_right, normal_left])
    const float* ctx = (b < 2) ? (fr + (size_t)b * CHW) : (fl + (size_t)(b - 2) * CHW);
    const float* geo = (b < 2) ? (nr + (size_t)b * 3 * HW) : (nl + (size_t)(b - 2) * 3 * HW);

#pragma unroll
    for (int i = 0; i < 32; i++) {
        int c = i * 4 + quad;
        sc[c][wl] = ctx[(size_t)c * HW + h * Ww + w0 + wl];
    }
    if (t < 192) sg[quad][wl] = geo[(size_t)quad * HW + h * Ww + w0 + wl];
    __syncthreads();

    const int obase = quad * 32;

    // nfeat: 3-channel conv
    {
        float g0 = sg[0][wl], g1 = sg[1][wl], g2 = sg[2][wl];
#pragma unroll 4
        for (int k = 0; k < 32; k++) {
            int o = obase + k;
            float a = bn[o] + wn[o * 3 + 0] * g0 + wn[o * 3 + 1] * g1 + wn[o * 3 + 2] * g2;
            nfeat_pl[((size_t)b * Cc + o) * HW + h * Ww + w0 + wl] = a;
        }
    }

    // value: 128x128 GEMM, 8-output chunks (weight rows wave-uniform)
    for (int kc = 0; kc < 32; kc += 8) {
        float acc[8];
#pragma unroll
        for (int j = 0; j < 8; j++) acc[j] = bv[obase + kc + j];
        for (int c = 0; c < Cc; c += 4) {
            float x0 = sc[c][wl], x1 = sc[c + 1][wl], x2 = sc[c + 2][wl], x3 = sc[c + 3][wl];
#pragma unroll
            for (int j = 0; j < 8; j++) {
                const float4 w4 = *(const float4*)(wv + (size_t)(obase + kc + j) * Cc + c);
                acc[j] += w4.x * x0 + w4.y * x1 + w4.z * x2 + w4.w * x3;
            }
        }
#pragma unroll
        for (int j = 0; j < 8; j++) {
            int o = obase + kc + j;
            value_pl[((size_t)b * Cc + o) * HW + h * Ww + w0 + wl] = acc[j];
        }
    }
}

// ---------------------------------------------------------------------------
// Kernel 2: q-projection (off_ctx 32 | off_geo 32 | attn 64), softmax over 8,
// keypoints ckp/gkp -> d_out, attn -> ws (planar).
// ---------------------------------------------------------------------------
__global__ __launch_bounds__(256) void qp_kernel(
    const float* __restrict__ mlq, const float* __restrict__ mrq,
    const float* __restrict__ woc, const float* __restrict__ boc,
    const float* __restrict__ wog, const float* __restrict__ bog,
    const float* __restrict__ wa,  const float* __restrict__ ba,
    const float* __restrict__ cap, const float* __restrict__ gap,
    float* __restrict__ attn_pl, float* __restrict__ ckp_out, float* __restrict__ gkp_out)
{
    __shared__ float sq[Cc][64];   // q tile, later overwritten with proj results
    const int t = threadIdx.x;
    const int wl = t & 63;
    const int quad = t >> 6;
    const int wt = blockIdx.x, h = blockIdx.y, b = blockIdx.z;
    const int w0 = wt * 64;

    const float* q = (b < 2) ? (mlq + (size_t)b * CHW) : (mrq + (size_t)(b - 2) * CHW);

#pragma unroll
    for (int i = 0; i < 32; i++) {
        int c = i * 4 + quad;
        sq[c][wl] = q[(size_t)c * HW + h * Ww + w0 + wl];
    }
    __syncthreads();

    // wave-uniform weight selection: wave0 -> off_ctx, wave1 -> off_geo, wave2/3 -> attn
    const float* wrow; const float* brow; int rbase;
    if (quad == 0)      { wrow = woc; brow = boc; rbase = 0; }
    else if (quad == 1) { wrow = wog; brow = bog; rbase = 0; }
    else                { wrow = wa;  brow = ba;  rbase = (quad - 2) * 32; }

    float acc[32];
#pragma unroll
    for (int k = 0; k < 32; k++) acc[k] = brow[rbase + k];
    for (int c = 0; c < Cc; c += 4) {
        float x0 = sq[c][wl], x1 = sq[c + 1][wl], x2 = sq[c + 2][wl], x3 = sq[c + 3][wl];
#pragma unroll
        for (int k = 0; k < 32; k++) {
            const float4 w4 = *(const float4*)(wrow + (size_t)(rbase + k) * Cc + c);
            acc[k] += w4.x * x0 + w4.y * x1 + w4.z * x2 + w4.w * x3;
        }
    }
    __syncthreads();                       // all reads of q tile done
#pragma unroll
    for (int k = 0; k < 32; k++) sq[quad * 32 + k][wl] = acc[k];  // proj[o][w]
    __syncthreads();

    // phase 2: per (g, w) pair
    for (int pi = t; pi < 512; pi += 256) {
        int g = pi >> 6;
        int w = pi & 63;
        // softmax over 8 attn logits
        float L[8], m = -1e30f;
#pragma unroll
        for (int j = 0; j < 8; j++) { L[j] = sq[64 + g * 8 + j][w]; m = fmaxf(m, L[j]); }
        float s = 0.f;
#pragma unroll
        for (int j = 0; j < 8; j++) { L[j] = expf(L[j] - m); s += L[j]; }
        float inv = 1.f / s;
#pragma unroll
        for (int j = 0; j < 8; j++)
            attn_pl[((((size_t)b * Gg + g) * 8 + j) * Hh + h) * Ww + w0 + w] = L[j] * inv;
        // keypoints
#pragma unroll
        for (int p = 0; p < 4; p++) {
            size_t kidx = ((((size_t)b * Gg + g) * Pp + p) * Hh + h) * Ww + w0 + w;
            float oc = sq[g * 4 + p][w];
            float og = sq[32 + g * 4 + p][w];
            float ck = fminf(fmaxf(cap[kidx] * 255.0f + oc, 0.f), 255.f);
            float gk = fminf(fmaxf(gap[kidx] * 255.0f + og, 0.f), 255.f);
            ckp_out[kidx] = ck;
            gkp_out[kidx] = gk;
        }
    }
}

// ---------------------------------------------------------------------------
// Kernel 3: deformable 1-D sampling + attention aggregation -> agg (planar)
// block = 256 threads (one per w), grid = (G, H, B2)
// ---------------------------------------------------------------------------
__global__ __launch_bounds__(256) void samp_kernel(
    const float* __restrict__ value_pl, const float* __restrict__ nfeat_pl,
    const float* __restrict__ attn_pl,
    const float* __restrict__ ckp, const float* __restrict__ gkp,
    float* __restrict__ agg_pl)
{
    __shared__ float vrow[Ww * 17];   // [w][d], pad 17 (17 coprime 32 -> conflict-free fill)
    __shared__ float nrow[Ww * 17];
    const int t = threadIdx.x;
    const int g = blockIdx.x, h = blockIdx.y, b = blockIdx.z;

#pragma unroll
    for (int r = 0; r < 16; r++) {
        vrow[t * 17 + r] = value_pl[(((size_t)b * Cc + g * 16 + r) * Hh + h) * Ww + t];
        nrow[t * 17 + r] = nfeat_pl[(((size_t)b * Cc + g * 16 + r) * Hh + h) * Ww + t];
    }
    __syncthreads();

    const int w = t;
    float a8[8], kp8[8];
#pragma unroll
    for (int j = 0; j < 8; j++)
        a8[j] = attn_pl[((((size_t)b * Gg + g) * 8 + j) * Hh + h) * Ww + w];
#pragma unroll
    for (int p = 0; p < 4; p++) {
        size_t kidx = ((((size_t)b * Gg + g) * Pp + p) * Hh + h) * Ww + w;
        kp8[p]     = ckp[kidx];
        kp8[4 + p] = gkp[kidx];
    }

    float acc[16];
#pragma unroll
    for (int d = 0; d < 16; d++) acc[d] = 0.f;

#pragma unroll
    for (int j = 0; j < 8; j++) {
        float x = kp8[j];                 // already clipped to [0, 255]
        int i0 = (int)floorf(x);
        int i1 = min(i0 + 1, Ww - 1);
        float tt = x - (float)i0;
        const float* src = (j < 4) ? vrow : nrow;
        float c0 = a8[j] * (1.f - tt);
        float c1 = a8[j] * tt;
#pragma unroll
        for (int d = 0; d < 16; d++)
            acc[d] += c0 * src[i0 * 17 + d] + c1 * src[i1 * 17 + d];
    }
#pragma unroll
    for (int d = 0; d < 16; d++)
        agg_pl[(((size_t)b * Cc + g * 16 + d) * Hh + h) * Ww + w] = acc[d];
}

// ---------------------------------------------------------------------------
// Kernel 4: upd = wo@agg + bo; x = q + upd*mask; LN(C); FFN (silu); out
// block = 256, grid = (W/64, H, B2)
// ---------------------------------------------------------------------------
__global__ __launch_bounds__(256) void ffn_kernel(
    const float* __restrict__ agg_pl,
    const float* __restrict__ mlq, const float* __restrict__ mrq,
    const float* __restrict__ gml, const float* __restrict__ gmr,
    const float* __restrict__ wo, const float* __restrict__ bo,
    const float* __restrict__ lnw, const float* __restrict__ lnb,
    const float* __restrict__ w1, const float* __restrict__ b1,
    const float* __restrict__ w2, const float* __restrict__ b2,
    float* __restrict__ out_ml, float* __restrict__ out_mr)
{
    __shared__ float xb[Cc][64];          // agg tile, later xn tile
    __shared__ float hb[Cc][64];          // FFN hidden chunk (128 rows)
    __shared__ float red[2][4][64];
    __shared__ float stats[2][64];
    const int t = threadIdx.x;
    const int wl = t & 63;
    const int quad = t >> 6;
    const int wt = blockIdx.x, h = blockIdx.y, b = blockIdx.z;
    const int w0 = wt * 64;
    const int obase = quad * 32;

#pragma unroll
    for (int i = 0; i < 32; i++) {
        int c = i * 4 + quad;
        xb[c][wl] = agg_pl[((size_t)b * Cc + c) * HW + h * Ww + w0 + wl];
    }
    __syncthreads();

    // out-projection: upd = wo @ agg + bo
    float xv[32];
    for (int kc = 0; kc < 32; kc += 8) {
        float acc[8];
#pragma unroll
        for (int j = 0; j < 8; j++) acc[j] = bo[obase + kc + j];
        for (int c = 0; c < Cc; c += 4) {
            float x0 = xb[c][wl], x1 = xb[c + 1][wl], x2 = xb[c + 2][wl], x3 = xb[c + 3][wl];
#pragma unroll
            for (int j = 0; j < 8; j++) {
                const float4 w4 = *(const float4*)(wo + (size_t)(obase + kc + j) * Cc + c);
                acc[j] += w4.x * x0 + w4.y * x1 + w4.z * x2 + w4.w * x3;
            }
        }
#pragma unroll
        for (int j = 0; j < 8; j++) xv[kc + j] = acc[j];
    }

    // mask + residual, LN partial sums
    const float* msk = (b < 2) ? (gml + (size_t)b * HW) : (gmr + (size_t)(b - 2) * HW);
    const float  mval = msk[h * Ww + w0 + wl];
    const float* q = (b < 2) ? (mlq + (size_t)b * CHW) : (mrq + (size_t)(b - 2) * CHW);
    float lsum = 0.f, lsq = 0.f;
#pragma unroll 4
    for (int k = 0; k < 32; k++) {
        int o = obase + k;
        float qv = q[(size_t)o * HW + h * Ww + w0 + wl];
        float x = qv + xv[k] * mval;
        xv[k] = x;
        lsum += x; lsq += x * x;
    }
    red[0][quad][wl] = lsum;
    red[1][quad][wl] = lsq;
    __syncthreads();
    if (t < 64) {
        float s  = red[0][0][wl] + red[0][1][wl] + red[0][2][wl] + red[0][3][wl];
        float ss = red[1][0][wl] + red[1][1][wl] + red[1][2][wl] + red[1][3][wl];
        float mu = s * (1.f / 128.f);
        float var = ss * (1.f / 128.f) - mu * mu;
        stats[0][wl] = mu;
        stats[1][wl] = rsqrtf(var + 1e-5f);
    }
    __syncthreads();
    const float mu = stats[0][wl], rstd = stats[1][wl];
#pragma unroll 4
    for (int k = 0; k < 32; k++) {
        int o = obase + k;
        xv[k] = (xv[k] - mu) * rstd * lnw[o] + lnb[o];   // xn (residual base)
    }
    // overwrite xb with xn (safe: both barriers above passed)
#pragma unroll 4
    for (int k = 0; k < 32; k++) xb[obase + k][wl] = xv[k];
    __syncthreads();

    // FFN: h1 = silu(w1 @ xn + b1) in two 128-row chunks; out += w2 @ act
    float oacc[32];
#pragma unroll
    for (int k = 0; k < 32; k++) oacc[k] = 0.f;

    for (int jc = 0; jc < 2; jc++) {
        for (int kc = 0; kc < 32; kc += 8) {
            float acc[8];
#pragma unroll
            for (int j = 0; j < 8; j++) acc[j] = b1[jc * 128 + obase + kc + j];
            for (int c = 0; c < Cc; c += 4) {
                float x0 = xb[c][wl], x1 = xb[c + 1][wl], x2 = xb[c + 2][wl], x3 = xb[c + 3][wl];
#pragma unroll
                for (int j = 0; j < 8; j++) {
                    const float4 w4 = *(const float4*)(w1 + (size_t)(jc * 128 + obase + kc + j) * Cc + c);
                    acc[j] += w4.x * x0 + w4.y * x1 + w4.z * x2 + w4.w * x3;
                }
            }
#pragma unroll
            for (int j = 0; j < 8; j++) {
                float hv = acc[j];
                hb[obase + kc + j][wl] = hv / (1.f + expf(-hv));   // h * sigmoid(h)
            }
        }
        __syncthreads();
        for (int kc = 0; kc < 32; kc += 8) {
            float acc[8];
#pragma unroll
            for (int j = 0; j < 8; j++) acc[j] = 0.f;
            for (int c = 0; c < Cc; c += 4) {
                float x0 = hb[c][wl], x1 = hb[c + 1][wl], x2 = hb[c + 2][wl], x3 = hb[c + 3][wl];
#pragma unroll
                for (int j = 0; j < 8; j++) {
                    const float4 w4 = *(const float4*)(w2 + (size_t)(obase + kc + j) * 256 + jc * 128 + c);
                    acc[j] += w4.x * x0 + w4.y * x1 + w4.z * x2 + w4.w * x3;
                }
            }
#pragma unroll
            for (int j = 0; j < 8; j++) oacc[kc + j] += acc[j];
        }
        __syncthreads();
    }

    float* outp = (b < 2) ? (out_ml + (size_t)b * CHW) : (out_mr + (size_t)(b - 2) * CHW);
#pragma unroll 4
    for (int k = 0; k < 32; k++) {
        int o = obase + k;
        outp[(size_t)o * HW + h * Ww + w0 + wl] = xv[k] + b2[o] + oacc[k];
    }
}

// ---------------------------------------------------------------------------
extern "C" void kernel_launch(void* const* d_in, const int* in_sizes, int n_in,
                              void* d_out, int out_size, void* d_ws, size_t ws_size,
                              hipStream_t stream)
{
    const float* match_l = (const float*)d_in[0];
    const float* match_r = (const float*)d_in[1];
    const float* feat_l  = (const float*)d_in[2];
    const float* feat_r  = (const float*)d_in[3];
    const float* norm_l  = (const float*)d_in[4];
    const float* norm_r  = (const float*)d_in[5];
    const float* gml     = (const float*)d_in[6];
    const float* gmr     = (const float*)d_in[7];
    const float* cap     = (const float*)d_in[8];
    const float* gap     = (const float*)d_in[9];
    const float* wv  = (const float*)d_in[10]; const float* bv  = (const float*)d_in[11];
    const float* wn  = (const float*)d_in[12]; const float* bn  = (const float*)d_in[13];
    const float* woc = (const float*)d_in[14]; const float* boc = (const float*)d_in[15];
    const float* wog = (const float*)d_in[16]; const float* bog = (const float*)d_in[17];
    const float* wa  = (const float*)d_in[18]; const float* ba  = (const float*)d_in[19];
    const float* wo  = (const float*)d_in[20]; const float* bo  = (const float*)d_in[21];
    const float* lnw = (const float*)d_in[22]; const float* lnb = (const float*)d_in[23];
    const float* w1  = (const float*)d_in[24]; const float* b1  = (const float*)d_in[25];
    const float* w2  = (const float*)d_in[26]; const float* b2  = (const float*)d_in[27];

    float* out = (float*)d_out;
    float* out_ml  = out;                               // (2,128,64,256)
    float* out_mr  = out + (size_t)2 * CHW;             // (2,128,64,256)
    float* ckp_out = out + (size_t)4 * CHW;             // (4,8,4,64,256)
    float* gkp_out = ckp_out + (size_t)B2v * Gg * Pp * HW;

    float* ws = (float*)d_ws;
    float* value_pl = ws;                                        // (4,128,64,256)
    float* nfeat_pl = value_pl + (size_t)B2v * Cc * HW;          // (4,128,64,256)
    float* attn_pl  = nfeat_pl + (size_t)B2v * Cc * HW;          // (4,8,8,64,256)
    float* agg_pl   = attn_pl + (size_t)B2v * Gg * 8 * HW;       // (4,128,64,256)

    dim3 blk(256);
    kv_kernel<<<dim3(4, Hh, B2v), blk, 0, stream>>>(
        feat_l, feat_r, norm_l, norm_r, wv, bv, wn, bn, value_pl, nfeat_pl);
    qp_kernel<<<dim3(4, Hh, B2v), blk, 0, stream>>>(
        match_l, match_r, woc, boc, wog, bog, wa, ba, cap, gap,
        attn_pl, ckp_out, gkp_out);
    samp_kernel<<<dim3(Gg, Hh, B2v), blk, 0, stream>>>(
        value_pl, nfeat_pl, attn_pl, ckp_out, gkp_out, agg_pl);
    ffn_kernel<<<dim3(4, Hh, B2v), blk, 0, stream>>>(
        agg_pl, match_l, match_r, gml, gmr, wo, bo, lnw, lnb,
        w1, b1, w2, b2, out_ml, out_mr);
}

// Round 2
// 500.833 us; speedup vs baseline: 2.1613x; 2.1613x over previous
//
#include <hip/hip_runtime.h>
#include <cstdint>
#include <math.h>

#define B2v 4
#define Cc  128
#define Hh  64
#define Ww  256
#define Gg  8
#define Pp  4
#define HW  (Hh*Ww)      // 16384
#define CHW (Cc*HW)      // 2097152

typedef float f32x4 __attribute__((ext_vector_type(4)));
typedef short s16x8 __attribute__((ext_vector_type(8)));
typedef short s16x4 __attribute__((ext_vector_type(4)));

__device__ __forceinline__ short f2bf(float x) {
    union { float f; unsigned u; } a; a.f = x;
    unsigned r = a.u + 0x7fffu + ((a.u >> 16) & 1u);   // RNE
    return (short)(r >> 16);
}
__device__ __forceinline__ float bf2f(short s) {
    union { unsigned u; float f; } a; a.u = ((unsigned)(unsigned short)s) << 16;
    return a.f;
}

// ---------------------------------------------------------------------------
// Kernel 0: convert GEMM weights f32 -> bf16 (row-major, same layout)
// ---------------------------------------------------------------------------
__global__ __launch_bounds__(256) void prep_kernel(
    const float* __restrict__ wo, const float* __restrict__ w1, const float* __restrict__ w2,
    short* __restrict__ wo_bf, short* __restrict__ w1_bf, short* __restrict__ w2_bf)
{
    int i = blockIdx.x * 256 + threadIdx.x;
    if (i < 16384) wo_bf[i] = f2bf(wo[i]);
    else if (i < 49152) w1_bf[i - 16384] = f2bf(w1[i - 16384]);
    else if (i < 81920) w2_bf[i - 49152] = f2bf(w2[i - 49152]);
}

// ---------------------------------------------------------------------------
// Kernel 1: value = wv @ ctx + bv ; nfeat = wn @ geo + bn   (planar outputs)
// ---------------------------------------------------------------------------
__global__ __launch_bounds__(256) void kv_kernel(
    const float* __restrict__ fl, const float* __restrict__ fr,
    const float* __restrict__ nl, const float* __restrict__ nr,
    const float* __restrict__ wv, const float* __restrict__ bv,
    const float* __restrict__ wn, const float* __restrict__ bn,
    float* __restrict__ value_pl, float* __restrict__ nfeat_pl)
{
    __shared__ float sc[Cc][64];
    __shared__ float sg[3][64];
    const int t   = threadIdx.x;
    const int wl  = t & 63;
    const int quad = t >> 6;
    const int wt = blockIdx.x, h = blockIdx.y, b = blockIdx.z;
    const int w0 = wt * 64;

    const float* ctx = (b < 2) ? (fr + (size_t)b * CHW) : (fl + (size_t)(b - 2) * CHW);
    const float* geo = (b < 2) ? (nr + (size_t)b * 3 * HW) : (nl + (size_t)(b - 2) * 3 * HW);

#pragma unroll
    for (int i = 0; i < 32; i++) {
        int c = i * 4 + quad;
        sc[c][wl] = ctx[(size_t)c * HW + h * Ww + w0 + wl];
    }
    if (t < 192) sg[quad][wl] = geo[(size_t)quad * HW + h * Ww + w0 + wl];
    __syncthreads();

    const int obase = quad * 32;

    {
        float g0 = sg[0][wl], g1 = sg[1][wl], g2 = sg[2][wl];
#pragma unroll 4
        for (int k = 0; k < 32; k++) {
            int o = obase + k;
            float a = bn[o] + wn[o * 3 + 0] * g0 + wn[o * 3 + 1] * g1 + wn[o * 3 + 2] * g2;
            nfeat_pl[((size_t)b * Cc + o) * HW + h * Ww + w0 + wl] = a;
        }
    }

    for (int kc = 0; kc < 32; kc += 8) {
        float acc[8];
#pragma unroll
        for (int j = 0; j < 8; j++) acc[j] = bv[obase + kc + j];
        for (int c = 0; c < Cc; c += 4) {
            float x0 = sc[c][wl], x1 = sc[c + 1][wl], x2 = sc[c + 2][wl], x3 = sc[c + 3][wl];
#pragma unroll
            for (int j = 0; j < 8; j++) {
                const float4 w4 = *(const float4*)(wv + (size_t)(obase + kc + j) * Cc + c);
                acc[j] += w4.x * x0 + w4.y * x1 + w4.z * x2 + w4.w * x3;
            }
        }
#pragma unroll
        for (int j = 0; j < 8; j++) {
            int o = obase + kc + j;
            value_pl[((size_t)b * Cc + o) * HW + h * Ww + w0 + wl] = acc[j];
        }
    }
}

// ---------------------------------------------------------------------------
// Kernel 2: q-projection (off_ctx 32 | off_geo 32 | attn 64), softmax,
// keypoints -> d_out, attn -> ws (planar).
// ---------------------------------------------------------------------------
__global__ __launch_bounds__(256) void qp_kernel(
    const float* __restrict__ mlq, const float* __restrict__ mrq,
    const float* __restrict__ woc, const float* __restrict__ boc,
    const float* __restrict__ wog, const float* __restrict__ bog,
    const float* __restrict__ wa,  const float* __restrict__ ba,
    const float* __restrict__ cap, const float* __restrict__ gap,
    float* __restrict__ attn_pl, float* __restrict__ ckp_out, float* __restrict__ gkp_out)
{
    __shared__ float sq[Cc][64];
    const int t = threadIdx.x;
    const int wl = t & 63;
    const int quad = t >> 6;
    const int wt = blockIdx.x, h = blockIdx.y, b = blockIdx.z;
    const int w0 = wt * 64;

    const float* q = (b < 2) ? (mlq + (size_t)b * CHW) : (mrq + (size_t)(b - 2) * CHW);

#pragma unroll
    for (int i = 0; i < 32; i++) {
        int c = i * 4 + quad;
        sq[c][wl] = q[(size_t)c * HW + h * Ww + w0 + wl];
    }
    __syncthreads();

    const float* wrow; const float* brow; int rbase;
    if (quad == 0)      { wrow = woc; brow = boc; rbase = 0; }
    else if (quad == 1) { wrow = wog; brow = bog; rbase = 0; }
    else                { wrow = wa;  brow = ba;  rbase = (quad - 2) * 32; }

    float acc[32];
#pragma unroll
    for (int k = 0; k < 32; k++) acc[k] = brow[rbase + k];
    for (int c = 0; c < Cc; c += 4) {
        float x0 = sq[c][wl], x1 = sq[c + 1][wl], x2 = sq[c + 2][wl], x3 = sq[c + 3][wl];
#pragma unroll
        for (int k = 0; k < 32; k++) {
            const float4 w4 = *(const float4*)(wrow + (size_t)(rbase + k) * Cc + c);
            acc[k] += w4.x * x0 + w4.y * x1 + w4.z * x2 + w4.w * x3;
        }
    }
    __syncthreads();
#pragma unroll
    for (int k = 0; k < 32; k++) sq[quad * 32 + k][wl] = acc[k];
    __syncthreads();

    for (int pi = t; pi < 512; pi += 256) {
        int g = pi >> 6;
        int w = pi & 63;
        float L[8], m = -1e30f;
#pragma unroll
        for (int j = 0; j < 8; j++) { L[j] = sq[64 + g * 8 + j][w]; m = fmaxf(m, L[j]); }
        float s = 0.f;
#pragma unroll
        for (int j = 0; j < 8; j++) { L[j] = expf(L[j] - m); s += L[j]; }
        float inv = 1.f / s;
#pragma unroll
        for (int j = 0; j < 8; j++)
            attn_pl[((((size_t)b * Gg + g) * 8 + j) * Hh + h) * Ww + w0 + w] = L[j] * inv;
#pragma unroll
        for (int p = 0; p < 4; p++) {
            size_t kidx = ((((size_t)b * Gg + g) * Pp + p) * Hh + h) * Ww + w0 + w;
            float oc = sq[g * 4 + p][w];
            float og = sq[32 + g * 4 + p][w];
            float ck = fminf(fmaxf(cap[kidx] * 255.0f + oc, 0.f), 255.f);
            float gk = fminf(fmaxf(gap[kidx] * 255.0f + og, 0.f), 255.f);
            ckp_out[kidx] = ck;
            gkp_out[kidx] = gk;
        }
    }
}

// ---------------------------------------------------------------------------
// Kernel 3: deformable sampling + aggregation -> agg bf16 [b][h][w][c]
// ---------------------------------------------------------------------------
__global__ __launch_bounds__(256) void samp_kernel(
    const float* __restrict__ value_pl, const float* __restrict__ nfeat_pl,
    const float* __restrict__ attn_pl,
    const float* __restrict__ ckp, const float* __restrict__ gkp,
    short* __restrict__ agg_bf)
{
    __shared__ float vrow[Ww * 17];
    __shared__ float nrow[Ww * 17];
    const int t = threadIdx.x;
    const int g = blockIdx.x, h = blockIdx.y, b = blockIdx.z;

#pragma unroll
    for (int r = 0; r < 16; r++) {
        vrow[t * 17 + r] = value_pl[(((size_t)b * Cc + g * 16 + r) * Hh + h) * Ww + t];
        nrow[t * 17 + r] = nfeat_pl[(((size_t)b * Cc + g * 16 + r) * Hh + h) * Ww + t];
    }
    __syncthreads();

    const int w = t;
    float a8[8], kp8[8];
#pragma unroll
    for (int j = 0; j < 8; j++)
        a8[j] = attn_pl[((((size_t)b * Gg + g) * 8 + j) * Hh + h) * Ww + w];
#pragma unroll
    for (int p = 0; p < 4; p++) {
        size_t kidx = ((((size_t)b * Gg + g) * Pp + p) * Hh + h) * Ww + w;
        kp8[p]     = ckp[kidx];
        kp8[4 + p] = gkp[kidx];
    }

    float acc[16];
#pragma unroll
    for (int d = 0; d < 16; d++) acc[d] = 0.f;

#pragma unroll
    for (int j = 0; j < 8; j++) {
        float x = kp8[j];
        int i0 = (int)floorf(x);
        int i1 = min(i0 + 1, Ww - 1);
        float tt = x - (float)i0;
        const float* src = (j < 4) ? vrow : nrow;
        float c0 = a8[j] * (1.f - tt);
        float c1 = a8[j] * tt;
#pragma unroll
        for (int d = 0; d < 16; d++)
            acc[d] += c0 * src[i0 * 17 + d] + c1 * src[i1 * 17 + d];
    }
    union { uint4 v[2]; short s[16]; } pk;
#pragma unroll
    for (int d = 0; d < 16; d++) pk.s[d] = f2bf(acc[d]);
    short* dst = agg_bf + ((size_t)((b * Hh + h) * Ww + w)) * 128 + g * 16;
    *(uint4*)(dst)     = pk.v[0];
    *(uint4*)(dst + 8) = pk.v[1];
}

// ---------------------------------------------------------------------------
// Kernel 4 (MFMA): out-proj + mask + residual + LN + FFN, bf16 16x16x32 MFMA
// block = 256 (4 waves), grid = (4, 64, 4). Per block: 64 pixels.
// LDS: sB [64][136] bf16 (agg tile -> x -> xn), hb [64][264] bf16, ~52.5 KB.
// ---------------------------------------------------------------------------
__global__ __launch_bounds__(256, 3) void ffn_mfma_kernel(
    const short* __restrict__ agg_bf,
    const float* __restrict__ mlq, const float* __restrict__ mrq,
    const float* __restrict__ gml, const float* __restrict__ gmr,
    const short* __restrict__ wo_bf, const float* __restrict__ bo,
    const float* __restrict__ lnw, const float* __restrict__ lnb,
    const short* __restrict__ w1_bf, const float* __restrict__ b1,
    const short* __restrict__ w2_bf, const float* __restrict__ b2,
    float* __restrict__ out_ml, float* __restrict__ out_mr)
{
    __shared__ short sB[64 * 136];     // pitch 136 bf16 (272 B, 16-aligned)
    __shared__ short hb[64 * 264];     // pitch 264 bf16 (528 B)
    __shared__ float red[2][4][64];
    __shared__ float stats[2][64];

    const int t    = threadIdx.x;
    const int lane = t & 63;
    const int ww   = t >> 6;          // wave id 0..3
    const int lm   = lane & 15;       // MFMA m/n index
    const int lq   = lane >> 4;       // MFMA k-quad / row-quad
    const int wt = blockIdx.x, h = blockIdx.y, b = blockIdx.z;
    const int w0 = wt * 64;
    const int hWw = h * Ww;

    // ---- stage agg tile (64 pixels x 128 ch, bf16) into sB[w][c] ----
    const uint4* gsrc = (const uint4*)(agg_bf + ((size_t)((b * Hh + h) * Ww + w0)) * 128);
#pragma unroll
    for (int i = 0; i < 4; i++) {
        int chunk = i * 256 + t;            // 1024 x 16B chunks
        int w = chunk >> 4, cc = chunk & 15;
        uint4 v = gsrc[chunk];
        *(uint4*)(&sB[w * 136 + cc * 8]) = v;
    }
    __syncthreads();

    // ---- GEMM1: upd = wo @ agg  (M=128, N=64, K=128) ----
    f32x4 acc1[2][4];
#pragma unroll
    for (int i = 0; i < 2; i++)
#pragma unroll
        for (int nt = 0; nt < 4; nt++) acc1[i][nt] = (f32x4){0.f, 0.f, 0.f, 0.f};

#pragma unroll
    for (int kk = 0; kk < 4; kk++) {
        s16x8 a[2], bf[4];
#pragma unroll
        for (int i = 0; i < 2; i++)
            a[i] = *(const s16x8*)(wo_bf + (size_t)((ww * 2 + i) * 16 + lm) * 128 + kk * 32 + lq * 8);
#pragma unroll
        for (int nt = 0; nt < 4; nt++)
            bf[nt] = *(const s16x8*)(&sB[(nt * 16 + lm) * 136 + kk * 32 + lq * 8]);
#pragma unroll
        for (int i = 0; i < 2; i++)
#pragma unroll
            for (int nt = 0; nt < 4; nt++)
                acc1[i][nt] = __builtin_amdgcn_mfma_f32_16x16x32_bf16(a[i], bf[nt], acc1[i][nt], 0, 0, 0);
    }
    __syncthreads();   // all waves done reading sB (agg)

    // ---- x = q + (upd + bo) * mask ; write x bf16 -> sB[w][c] ----
    const float* msk = (b < 2) ? (gml + (size_t)b * HW) : (gmr + (size_t)(b - 2) * HW);
    const float* q   = (b < 2) ? (mlq + (size_t)b * CHW) : (mrq + (size_t)(b - 2) * CHW);
    float mvals[4];
#pragma unroll
    for (int nt = 0; nt < 4; nt++) mvals[nt] = msk[hWw + w0 + nt * 16 + lm];

#pragma unroll
    for (int i = 0; i < 2; i++) {
        const int ob = ww * 32 + i * 16 + lq * 4;
        float bias[4];
#pragma unroll
        for (int r = 0; r < 4; r++) bias[r] = bo[ob + r];
#pragma unroll
        for (int nt = 0; nt < 4; nt++) {
            const int wg = nt * 16 + lm;
            s16x4 pack;
#pragma unroll
            for (int r = 0; r < 4; r++) {
                float upd = acc1[i][nt][r] + bias[r];
                float qv = q[(size_t)(ob + r) * HW + hWw + w0 + wg];
                float x = qv + upd * mvals[nt];
                pack[r] = f2bf(x);
            }
            *(s16x4*)(&sB[wg * 136 + ob]) = pack;
        }
    }
    __syncthreads();

    // ---- LayerNorm over channels (quad-scheme), write xn bf16 back ----
    {
        const int quad = ww, wl = lane;   // thread owns (pixel wl, channels quad*32..+31)
        float xv[32];
#pragma unroll
        for (int c8 = 0; c8 < 4; c8++) {
            s16x8 v = *(const s16x8*)(&sB[wl * 136 + quad * 32 + c8 * 8]);
#pragma unroll
            for (int j = 0; j < 8; j++) xv[c8 * 8 + j] = bf2f(v[j]);
        }
        float lsum = 0.f, lsq = 0.f;
#pragma unroll
        for (int k = 0; k < 32; k++) { lsum += xv[k]; lsq += xv[k] * xv[k]; }
        red[0][quad][wl] = lsum;
        red[1][quad][wl] = lsq;
        __syncthreads();
        if (t < 64) {
            float s  = red[0][0][wl] + red[0][1][wl] + red[0][2][wl] + red[0][3][wl];
            float ss = red[1][0][wl] + red[1][1][wl] + red[1][2][wl] + red[1][3][wl];
            float mu = s * (1.f / 128.f);
            float var = ss * (1.f / 128.f) - mu * mu;
            stats[0][wl] = mu;
            stats[1][wl] = rsqrtf(var + 1e-5f);
        }
        __syncthreads();
        const float mu = stats[0][wl], rstd = stats[1][wl];
#pragma unroll
        for (int c8 = 0; c8 < 4; c8++) {
            s16x8 pack;
#pragma unroll
            for (int j = 0; j < 8; j++) {
                int c = quad * 32 + c8 * 8 + j;
                float xn = (xv[c8 * 8 + j] - mu) * rstd * lnw[c] + lnb[c];
                pack[j] = f2bf(xn);
            }
            *(s16x8*)(&sB[wl * 136 + quad * 32 + c8 * 8]) = pack;
        }
    }
    __syncthreads();

    // ---- GEMM2: h = silu(w1 @ xn + b1)  (M=256, N=64, K=128) -> hb[w][j] ----
    {
        f32x4 acc2[4][4];
#pragma unroll
        for (int i = 0; i < 4; i++)
#pragma unroll
            for (int nt = 0; nt < 4; nt++) acc2[i][nt] = (f32x4){0.f, 0.f, 0.f, 0.f};

#pragma unroll
        for (int kk = 0; kk < 4; kk++) {
            s16x8 a[4], bf[4];
#pragma unroll
            for (int i = 0; i < 4; i++)
                a[i] = *(const s16x8*)(w1_bf + (size_t)((ww * 4 + i) * 16 + lm) * 128 + kk * 32 + lq * 8);
#pragma unroll
            for (int nt = 0; nt < 4; nt++)
                bf[nt] = *(const s16x8*)(&sB[(nt * 16 + lm) * 136 + kk * 32 + lq * 8]);
#pragma unroll
            for (int i = 0; i < 4; i++)
#pragma unroll
                for (int nt = 0; nt < 4; nt++)
                    acc2[i][nt] = __builtin_amdgcn_mfma_f32_16x16x32_bf16(a[i], bf[nt], acc2[i][nt], 0, 0, 0);
        }
#pragma unroll
        for (int i = 0; i < 4; i++) {
            const int jb = ww * 64 + i * 16 + lq * 4;
            float bias[4];
#pragma unroll
            for (int r = 0; r < 4; r++) bias[r] = b1[jb + r];
#pragma unroll
            for (int nt = 0; nt < 4; nt++) {
                const int wg = nt * 16 + lm;
                s16x4 pack;
#pragma unroll
                for (int r = 0; r < 4; r++) {
                    float hv = acc2[i][nt][r] + bias[r];
                    float act = hv / (1.f + expf(-hv));
                    pack[r] = f2bf(act);
                }
                *(s16x4*)(&hb[wg * 264 + jb]) = pack;
            }
        }
    }
    __syncthreads();

    // ---- GEMM3: y = xn + w2 @ act + b2  (M=128, N=64, K=256) ----
    f32x4 acc3[2][4];
#pragma unroll
    for (int i = 0; i < 2; i++)
#pragma unroll
        for (int nt = 0; nt < 4; nt++) acc3[i][nt] = (f32x4){0.f, 0.f, 0.f, 0.f};

#pragma unroll
    for (int kk = 0; kk < 8; kk++) {
        s16x8 a[2], bf[4];
#pragma unroll
        for (int i = 0; i < 2; i++)
            a[i] = *(const s16x8*)(w2_bf + (size_t)((ww * 2 + i) * 16 + lm) * 256 + kk * 32 + lq * 8);
#pragma unroll
        for (int nt = 0; nt < 4; nt++)
            bf[nt] = *(const s16x8*)(&hb[(nt * 16 + lm) * 264 + kk * 32 + lq * 8]);
#pragma unroll
        for (int i = 0; i < 2; i++)
#pragma unroll
            for (int nt = 0; nt < 4; nt++)
                acc3[i][nt] = __builtin_amdgcn_mfma_f32_16x16x32_bf16(a[i], bf[nt], acc3[i][nt], 0, 0, 0);
    }

    float* outp = (b < 2) ? (out_ml + (size_t)b * CHW) : (out_mr + (size_t)(b - 2) * CHW);
#pragma unroll
    for (int i = 0; i < 2; i++) {
        const int ob = ww * 32 + i * 16 + lq * 4;
        float b2v[4];
#pragma unroll
        for (int r = 0; r < 4; r++) b2v[r] = b2[ob + r];
#pragma unroll
        for (int nt = 0; nt < 4; nt++) {
            const int wg = nt * 16 + lm;
            s16x4 xn4 = *(const s16x4*)(&sB[wg * 136 + ob]);
#pragma unroll
            for (int r = 0; r < 4; r++) {
                float y = bf2f(xn4[r]) + b2v[r] + acc3[i][nt][r];
                outp[(size_t)(ob + r) * HW + hWw + w0 + wg] = y;
            }
        }
    }
}

// ---------------------------------------------------------------------------
extern "C" void kernel_launch(void* const* d_in, const int* in_sizes, int n_in,
                              void* d_out, int out_size, void* d_ws, size_t ws_size,
                              hipStream_t stream)
{
    const float* match_l = (const float*)d_in[0];
    const float* match_r = (const float*)d_in[1];
    const float* feat_l  = (const float*)d_in[2];
    const float* feat_r  = (const float*)d_in[3];
    const float* norm_l  = (const float*)d_in[4];
    const float* norm_r  = (const float*)d_in[5];
    const float* gml     = (const float*)d_in[6];
    const float* gmr     = (const float*)d_in[7];
    const float* cap     = (const float*)d_in[8];
    const float* gap     = (const float*)d_in[9];
    const float* wv  = (const float*)d_in[10]; const float* bv  = (const float*)d_in[11];
    const float* wn  = (const float*)d_in[12]; const float* bn  = (const float*)d_in[13];
    const float* woc = (const float*)d_in[14]; const float* boc = (const float*)d_in[15];
    const float* wog = (const float*)d_in[16]; const float* bog = (const float*)d_in[17];
    const float* wa  = (const float*)d_in[18]; const float* ba  = (const float*)d_in[19];
    const float* wo  = (const float*)d_in[20]; const float* bo  = (const float*)d_in[21];
    const float* lnw = (const float*)d_in[22]; const float* lnb = (const float*)d_in[23];
    const float* w1  = (const float*)d_in[24]; const float* b1  = (const float*)d_in[25];
    const float* w2  = (const float*)d_in[26]; const float* b2  = (const float*)d_in[27];

    float* out = (float*)d_out;
    float* out_ml  = out;
    float* out_mr  = out + (size_t)2 * CHW;
    float* ckp_out = out + (size_t)4 * CHW;
    float* gkp_out = ckp_out + (size_t)B2v * Gg * Pp * HW;

    float* ws = (float*)d_ws;
    float* value_pl = ws;                                        // 4*128*HW f32
    float* nfeat_pl = value_pl + (size_t)B2v * Cc * HW;          // 4*128*HW f32
    float* attn_pl  = nfeat_pl + (size_t)B2v * Cc * HW;          // 4*64*HW f32
    short* agg_bf   = (short*)(attn_pl + (size_t)B2v * Gg * 8 * HW);  // 4*HW*128 bf16
    short* wo_bf    = agg_bf + (size_t)B2v * HW * Cc;
    short* w1_bf    = wo_bf + 16384;
    short* w2_bf    = w1_bf + 32768;

    dim3 blk(256);
    prep_kernel<<<dim3(320), blk, 0, stream>>>(wo, w1, w2, wo_bf, w1_bf, w2_bf);
    kv_kernel<<<dim3(4, Hh, B2v), blk, 0, stream>>>(
        feat_l, feat_r, norm_l, norm_r, wv, bv, wn, bn, value_pl, nfeat_pl);
    qp_kernel<<<dim3(4, Hh, B2v), blk, 0, stream>>>(
        match_l, match_r, woc, boc, wog, bog, wa, ba, cap, gap,
        attn_pl, ckp_out, gkp_out);
    samp_kernel<<<dim3(Gg, Hh, B2v), blk, 0, stream>>>(
        value_pl, nfeat_pl, attn_pl, ckp_out, gkp_out, agg_bf);
    ffn_mfma_kernel<<<dim3(4, Hh, B2v), blk, 0, stream>>>(
        agg_bf, match_l, match_r, gml, gmr, wo_bf, bo, lnw, lnb,
        w1_bf, b1, w2_bf, b2, out_ml, out_mr);
}

// Round 3
// 281.089 us; speedup vs baseline: 3.8510x; 1.7818x over previous
//
#include <hip/hip_runtime.h>
#include <cstdint>
#include <math.h>

#define B2v 4
#define Cc  128
#define Hh  64
#define Ww  256
#define Gg  8
#define Pp  4
#define HW  (Hh*Ww)      // 16384
#define CHW (Cc*HW)      // 2097152

typedef float f32x4 __attribute__((ext_vector_type(4)));
typedef short s16x8 __attribute__((ext_vector_type(8)));
typedef short s16x4 __attribute__((ext_vector_type(4)));

__device__ __forceinline__ short f2bf(float x) {
    union { float f; unsigned u; } a; a.f = x;
    unsigned r = a.u + 0x7fffu + ((a.u >> 16) & 1u);   // RNE
    return (short)(r >> 16);
}
__device__ __forceinline__ float bf2f(short s) {
    union { unsigned u; float f; } a; a.u = ((unsigned)(unsigned short)s) << 16;
    return a.f;
}

// ---------------------------------------------------------------------------
// Kernel 0: weights f32 -> bf16. Layout in wbf:
// [0,16384) wv | [16384,32768) wq=[woc;wog;wa] | [32768,49152) wo
// [49152,81920) w1 | [81920,114688) w2 ; bq[128] = [boc;bog;ba] (f32)
// ---------------------------------------------------------------------------
__global__ __launch_bounds__(256) void prep_kernel(
    const float* __restrict__ wv, const float* __restrict__ woc,
    const float* __restrict__ wog, const float* __restrict__ wa,
    const float* __restrict__ wo, const float* __restrict__ w1,
    const float* __restrict__ w2,
    const float* __restrict__ boc, const float* __restrict__ bog,
    const float* __restrict__ ba,
    short* __restrict__ wbf, float* __restrict__ bq)
{
    int i = blockIdx.x * 256 + threadIdx.x;
    if (i < 16384) wbf[i] = f2bf(wv[i]);
    else if (i < 32768) {
        int j = i - 16384; int r = j >> 7, c = j & 127;
        float v = (r < 32) ? woc[r * 128 + c] : (r < 64) ? wog[(r - 32) * 128 + c]
                                              : wa[(r - 64) * 128 + c];
        wbf[i] = f2bf(v);
    }
    else if (i < 49152)  wbf[i] = f2bf(wo[i - 32768]);
    else if (i < 81920)  wbf[i] = f2bf(w1[i - 49152]);
    else if (i < 114688) wbf[i] = f2bf(w2[i - 81920]);
    else if (i < 114816) {
        int r = i - 114688;
        bq[r] = (r < 32) ? boc[r] : (r < 64) ? bog[r - 32] : ba[r - 64];
    }
}

// ---------------------------------------------------------------------------
// Kernel 1: pack activations planar f32 -> pixel-major bf16 [b][h][w][c].
// z<4: q_bf from match (b<2 -> ml); z>=4: ctx_bf from feat (CROSS: b<2 -> fr)
// ---------------------------------------------------------------------------
__global__ __launch_bounds__(256) void pack_kernel(
    const float* __restrict__ ml, const float* __restrict__ mr,
    const float* __restrict__ fl, const float* __restrict__ fr,
    short* __restrict__ q_bf, short* __restrict__ ctx_bf)
{
    __shared__ float sc[128 * 65];
    const int t = threadIdx.x;
    const int wl = t & 63;
    const int quad = t >> 6;
    const int wt = blockIdx.x, h = blockIdx.y, z = blockIdx.z;
    const int w0 = wt * 64;
    const int b = (z < 4) ? z : z - 4;

    const float* src; short* dst;
    if (z < 4) { src = (b < 2) ? ml + (size_t)b * CHW : mr + (size_t)(b - 2) * CHW; dst = q_bf; }
    else       { src = (b < 2) ? fr + (size_t)b * CHW : fl + (size_t)(b - 2) * CHW; dst = ctx_bf; }
    dst += ((size_t)(b * Hh + h) * Ww + w0) * 128;
    const size_t hw = (size_t)h * Ww + w0 + wl;

#pragma unroll
    for (int i = 0; i < 32; i++) {
        int c = i * 4 + quad;
        sc[c * 65 + wl] = src[(size_t)c * HW + hw];
    }
    __syncthreads();
#pragma unroll
    for (int i = 0; i < 4; i++) {
        int ch = i * 256 + t;
        int w = ch >> 4, cc = ch & 15;
        union { uint4 v; short s[8]; } pk;
#pragma unroll
        for (int j = 0; j < 8; j++) pk.s[j] = f2bf(sc[(cc * 8 + j) * 65 + w]);
        *(uint4*)(dst + (size_t)w * 128 + cc * 8) = pk.v;
    }
}

// ---------------------------------------------------------------------------
// Kernel 2 (MFMA): value = wv @ ctx + bv -> planar bf16;
//                  nfeat = wn @ geo + bn -> planar bf16
// ---------------------------------------------------------------------------
__global__ __launch_bounds__(256, 4) void kv_mfma_kernel(
    const short* __restrict__ ctx_bf,
    const float* __restrict__ nl, const float* __restrict__ nr,
    const short* __restrict__ wv_bf, const float* __restrict__ bv,
    const float* __restrict__ wn, const float* __restrict__ bn,
    short* __restrict__ value_pl, short* __restrict__ nfeat_pl)
{
    __shared__ short sB[64 * 136];
    __shared__ float sg[3][64];
    __shared__ float swn[128 * 3 + 128];
    const int t = threadIdx.x;
    const int lane = t & 63;
    const int ww = t >> 6;
    const int lm = lane & 15, lq = lane >> 4;
    const int wt = blockIdx.x, h = blockIdx.y, b = blockIdx.z;
    const int w0 = wt * 64;
    const int hWw = h * Ww;

    const uint4* gsrc = (const uint4*)(ctx_bf + ((size_t)(b * Hh + h) * Ww + w0) * 128);
#pragma unroll
    for (int i = 0; i < 4; i++) {
        int ch = i * 256 + t;
        int w = ch >> 4, cc = ch & 15;
        *(uint4*)(&sB[w * 136 + cc * 8]) = gsrc[ch];
    }
    const float* geo = (b < 2) ? nr + (size_t)b * 3 * HW : nl + (size_t)(b - 2) * 3 * HW;
    if (t < 192) sg[t >> 6][lane] = geo[(size_t)(t >> 6) * HW + hWw + w0 + lane];
    if (t < 128) {
        swn[t * 3]     = wn[t * 3];
        swn[t * 3 + 1] = wn[t * 3 + 1];
        swn[t * 3 + 2] = wn[t * 3 + 2];
        swn[384 + t]   = bn[t];
    }
    __syncthreads();

    f32x4 acc[2][4];
#pragma unroll
    for (int i = 0; i < 2; i++)
#pragma unroll
        for (int nt = 0; nt < 4; nt++) acc[i][nt] = (f32x4){0.f, 0.f, 0.f, 0.f};

#pragma unroll
    for (int kk = 0; kk < 4; kk++) {
        s16x8 a[2], bf[4];
#pragma unroll
        for (int i = 0; i < 2; i++)
            a[i] = *(const s16x8*)(wv_bf + (size_t)((ww * 2 + i) * 16 + lm) * 128 + kk * 32 + lq * 8);
#pragma unroll
        for (int nt = 0; nt < 4; nt++)
            bf[nt] = *(const s16x8*)(&sB[(nt * 16 + lm) * 136 + kk * 32 + lq * 8]);
#pragma unroll
        for (int i = 0; i < 2; i++)
#pragma unroll
            for (int nt = 0; nt < 4; nt++)
                acc[i][nt] = __builtin_amdgcn_mfma_f32_16x16x32_bf16(a[i], bf[nt], acc[i][nt], 0, 0, 0);
    }

    // value -> planar bf16 (C-layout direct stores, 16-lane contiguous segments)
#pragma unroll
    for (int i = 0; i < 2; i++) {
        const int ob = ww * 32 + i * 16 + lq * 4;
        float bias[4];
#pragma unroll
        for (int r = 0; r < 4; r++) bias[r] = bv[ob + r];
#pragma unroll
        for (int nt = 0; nt < 4; nt++) {
            const int wg = nt * 16 + lm;
#pragma unroll
            for (int r = 0; r < 4; r++)
                value_pl[(size_t)(b * Cc + ob + r) * HW + hWw + w0 + wg] =
                    f2bf(acc[i][nt][r] + bias[r]);
        }
    }

    // nfeat: trivial 3-channel conv, planar bf16
    {
        float g0 = sg[0][lane], g1 = sg[1][lane], g2 = sg[2][lane];
#pragma unroll 4
        for (int k = 0; k < 32; k++) {
            int o = ww * 32 + k;
            float v = swn[384 + o] + swn[o * 3] * g0 + swn[o * 3 + 1] * g1 + swn[o * 3 + 2] * g2;
            nfeat_pl[(size_t)(b * Cc + o) * HW + hWw + w0 + lane] = f2bf(v);
        }
    }
}

// ---------------------------------------------------------------------------
// Kernel 3 (MFMA): proj = wq @ q + bq (128 rows: off_ctx|off_geo|attn),
// softmax over 8, keypoints -> d_out, attn -> ws (planar f32).
// ---------------------------------------------------------------------------
__global__ __launch_bounds__(256, 3) void qp_mfma_kernel(
    const short* __restrict__ q_bf,
    const short* __restrict__ wq_bf, const float* __restrict__ bq,
    const float* __restrict__ cap, const float* __restrict__ gap,
    float* __restrict__ attn_pl, float* __restrict__ ckp_out, float* __restrict__ gkp_out)
{
    __shared__ short sB[64 * 136];
    __shared__ float sP[128 * 64];
    const int t = threadIdx.x;
    const int lane = t & 63;
    const int ww = t >> 6;
    const int lm = lane & 15, lq = lane >> 4;
    const int wt = blockIdx.x, h = blockIdx.y, b = blockIdx.z;
    const int w0 = wt * 64;

    const uint4* gsrc = (const uint4*)(q_bf + ((size_t)(b * Hh + h) * Ww + w0) * 128);
#pragma unroll
    for (int i = 0; i < 4; i++) {
        int ch = i * 256 + t;
        int w = ch >> 4, cc = ch & 15;
        *(uint4*)(&sB[w * 136 + cc * 8]) = gsrc[ch];
    }
    __syncthreads();

    f32x4 acc[2][4];
#pragma unroll
    for (int i = 0; i < 2; i++)
#pragma unroll
        for (int nt = 0; nt < 4; nt++) acc[i][nt] = (f32x4){0.f, 0.f, 0.f, 0.f};

#pragma unroll
    for (int kk = 0; kk < 4; kk++) {
        s16x8 a[2], bf[4];
#pragma unroll
        for (int i = 0; i < 2; i++)
            a[i] = *(const s16x8*)(wq_bf + (size_t)((ww * 2 + i) * 16 + lm) * 128 + kk * 32 + lq * 8);
#pragma unroll
        for (int nt = 0; nt < 4; nt++)
            bf[nt] = *(const s16x8*)(&sB[(nt * 16 + lm) * 136 + kk * 32 + lq * 8]);
#pragma unroll
        for (int i = 0; i < 2; i++)
#pragma unroll
            for (int nt = 0; nt < 4; nt++)
                acc[i][nt] = __builtin_amdgcn_mfma_f32_16x16x32_bf16(a[i], bf[nt], acc[i][nt], 0, 0, 0);
    }

#pragma unroll
    for (int i = 0; i < 2; i++) {
        const int ob = ww * 32 + i * 16 + lq * 4;
        float bias[4];
#pragma unroll
        for (int r = 0; r < 4; r++) bias[r] = bq[ob + r];
#pragma unroll
        for (int nt = 0; nt < 4; nt++) {
            const int wg = nt * 16 + lm;
#pragma unroll
            for (int r = 0; r < 4; r++)
                sP[(ob + r) * 64 + wg] = acc[i][nt][r] + bias[r];
        }
    }
    __syncthreads();

    // phase 2: per (g, w)
    for (int pi = t; pi < 512; pi += 256) {
        int g = pi >> 6;
        int w = pi & 63;
        float L[8], m = -1e30f;
#pragma unroll
        for (int j = 0; j < 8; j++) { L[j] = sP[(64 + g * 8 + j) * 64 + w]; m = fmaxf(m, L[j]); }
        float s = 0.f;
#pragma unroll
        for (int j = 0; j < 8; j++) { L[j] = expf(L[j] - m); s += L[j]; }
        float inv = 1.f / s;
#pragma unroll
        for (int j = 0; j < 8; j++)
            attn_pl[((((size_t)b * Gg + g) * 8 + j) * Hh + h) * Ww + w0 + w] = L[j] * inv;
#pragma unroll
        for (int p = 0; p < 4; p++) {
            size_t kidx = ((((size_t)b * Gg + g) * Pp + p) * Hh + h) * Ww + w0 + w;
            float oc = sP[(g * 4 + p) * 64 + w];
            float og = sP[(32 + g * 4 + p) * 64 + w];
            float ck = fminf(fmaxf(cap[kidx] * 255.0f + oc, 0.f), 255.f);
            float gk = fminf(fmaxf(gap[kidx] * 255.0f + og, 0.f), 255.f);
            ckp_out[kidx] = ck;
            gkp_out[kidx] = gk;
        }
    }
}

// ---------------------------------------------------------------------------
// Kernel 4: deformable sampling + aggregation -> agg bf16 [b][h][w][c]
// value/nfeat now planar bf16
// ---------------------------------------------------------------------------
__global__ __launch_bounds__(256) void samp_kernel(
    const short* __restrict__ value_pl, const short* __restrict__ nfeat_pl,
    const float* __restrict__ attn_pl,
    const float* __restrict__ ckp, const float* __restrict__ gkp,
    short* __restrict__ agg_bf)
{
    __shared__ float vrow[Ww * 17];
    __shared__ float nrow[Ww * 17];
    const int t = threadIdx.x;
    const int g = blockIdx.x, h = blockIdx.y, b = blockIdx.z;

#pragma unroll
    for (int r = 0; r < 16; r++) {
        vrow[t * 17 + r] = bf2f(value_pl[(((size_t)b * Cc + g * 16 + r) * Hh + h) * Ww + t]);
        nrow[t * 17 + r] = bf2f(nfeat_pl[(((size_t)b * Cc + g * 16 + r) * Hh + h) * Ww + t]);
    }
    __syncthreads();

    const int w = t;
    float a8[8], kp8[8];
#pragma unroll
    for (int j = 0; j < 8; j++)
        a8[j] = attn_pl[((((size_t)b * Gg + g) * 8 + j) * Hh + h) * Ww + w];
#pragma unroll
    for (int p = 0; p < 4; p++) {
        size_t kidx = ((((size_t)b * Gg + g) * Pp + p) * Hh + h) * Ww + w;
        kp8[p]     = ckp[kidx];
        kp8[4 + p] = gkp[kidx];
    }

    float acc[16];
#pragma unroll
    for (int d = 0; d < 16; d++) acc[d] = 0.f;

#pragma unroll
    for (int j = 0; j < 8; j++) {
        float x = kp8[j];
        int i0 = (int)floorf(x);
        int i1 = min(i0 + 1, Ww - 1);
        float tt = x - (float)i0;
        const float* src = (j < 4) ? vrow : nrow;
        float c0 = a8[j] * (1.f - tt);
        float c1 = a8[j] * tt;
#pragma unroll
        for (int d = 0; d < 16; d++)
            acc[d] += c0 * src[i0 * 17 + d] + c1 * src[i1 * 17 + d];
    }
    union { uint4 v[2]; short s[16]; } pk;
#pragma unroll
    for (int d = 0; d < 16; d++) pk.s[d] = f2bf(acc[d]);
    short* dst = agg_bf + ((size_t)((b * Hh + h) * Ww + w)) * 128 + g * 16;
    *(uint4*)(dst)     = pk.v[0];
    *(uint4*)(dst + 8) = pk.v[1];
}

// ---------------------------------------------------------------------------
// Kernel 5 (MFMA): out-proj + mask + residual + LN + FFN  (unchanged r2)
// ---------------------------------------------------------------------------
__global__ __launch_bounds__(256, 3) void ffn_mfma_kernel(
    const short* __restrict__ agg_bf,
    const float* __restrict__ mlq, const float* __restrict__ mrq,
    const float* __restrict__ gml, const float* __restrict__ gmr,
    const short* __restrict__ wo_bf, const float* __restrict__ bo,
    const float* __restrict__ lnw, const float* __restrict__ lnb,
    const short* __restrict__ w1_bf, const float* __restrict__ b1,
    const short* __restrict__ w2_bf, const float* __restrict__ b2,
    float* __restrict__ out_ml, float* __restrict__ out_mr)
{
    __shared__ short sB[64 * 136];
    __shared__ short hb[64 * 264];
    __shared__ float red[2][4][64];
    __shared__ float stats[2][64];

    const int t    = threadIdx.x;
    const int lane = t & 63;
    const int ww   = t >> 6;
    const int lm   = lane & 15;
    const int lq   = lane >> 4;
    const int wt = blockIdx.x, h = blockIdx.y, b = blockIdx.z;
    const int w0 = wt * 64;
    const int hWw = h * Ww;

    const uint4* gsrc = (const uint4*)(agg_bf + ((size_t)((b * Hh + h) * Ww + w0)) * 128);
#pragma unroll
    for (int i = 0; i < 4; i++) {
        int chunk = i * 256 + t;
        int w = chunk >> 4, cc = chunk & 15;
        uint4 v = gsrc[chunk];
        *(uint4*)(&sB[w * 136 + cc * 8]) = v;
    }
    __syncthreads();

    f32x4 acc1[2][4];
#pragma unroll
    for (int i = 0; i < 2; i++)
#pragma unroll
        for (int nt = 0; nt < 4; nt++) acc1[i][nt] = (f32x4){0.f, 0.f, 0.f, 0.f};

#pragma unroll
    for (int kk = 0; kk < 4; kk++) {
        s16x8 a[2], bf[4];
#pragma unroll
        for (int i = 0; i < 2; i++)
            a[i] = *(const s16x8*)(wo_bf + (size_t)((ww * 2 + i) * 16 + lm) * 128 + kk * 32 + lq * 8);
#pragma unroll
        for (int nt = 0; nt < 4; nt++)
            bf[nt] = *(const s16x8*)(&sB[(nt * 16 + lm) * 136 + kk * 32 + lq * 8]);
#pragma unroll
        for (int i = 0; i < 2; i++)
#pragma unroll
            for (int nt = 0; nt < 4; nt++)
                acc1[i][nt] = __builtin_amdgcn_mfma_f32_16x16x32_bf16(a[i], bf[nt], acc1[i][nt], 0, 0, 0);
    }
    __syncthreads();

    const float* msk = (b < 2) ? (gml + (size_t)b * HW) : (gmr + (size_t)(b - 2) * HW);
    const float* q   = (b < 2) ? (mlq + (size_t)b * CHW) : (mrq + (size_t)(b - 2) * CHW);
    float mvals[4];
#pragma unroll
    for (int nt = 0; nt < 4; nt++) mvals[nt] = msk[hWw + w0 + nt * 16 + lm];

#pragma unroll
    for (int i = 0; i < 2; i++) {
        const int ob = ww * 32 + i * 16 + lq * 4;
        float bias[4];
#pragma unroll
        for (int r = 0; r < 4; r++) bias[r] = bo[ob + r];
#pragma unroll
        for (int nt = 0; nt < 4; nt++) {
            const int wg = nt * 16 + lm;
            s16x4 pack;
#pragma unroll
            for (int r = 0; r < 4; r++) {
                float upd = acc1[i][nt][r] + bias[r];
                float qv = q[(size_t)(ob + r) * HW + hWw + w0 + wg];
                float x = qv + upd * mvals[nt];
                pack[r] = f2bf(x);
            }
            *(s16x4*)(&sB[wg * 136 + ob]) = pack;
        }
    }
    __syncthreads();

    {
        const int quad = ww, wl = lane;
        float xv[32];
#pragma unroll
        for (int c8 = 0; c8 < 4; c8++) {
            s16x8 v = *(const s16x8*)(&sB[wl * 136 + quad * 32 + c8 * 8]);
#pragma unroll
            for (int j = 0; j < 8; j++) xv[c8 * 8 + j] = bf2f(v[j]);
        }
        float lsum = 0.f, lsq = 0.f;
#pragma unroll
        for (int k = 0; k < 32; k++) { lsum += xv[k]; lsq += xv[k] * xv[k]; }
        red[0][quad][wl] = lsum;
        red[1][quad][wl] = lsq;
        __syncthreads();
        if (t < 64) {
            float s  = red[0][0][wl] + red[0][1][wl] + red[0][2][wl] + red[0][3][wl];
            float ss = red[1][0][wl] + red[1][1][wl] + red[1][2][wl] + red[1][3][wl];
            float mu = s * (1.f / 128.f);
            float var = ss * (1.f / 128.f) - mu * mu;
            stats[0][wl] = mu;
            stats[1][wl] = rsqrtf(var + 1e-5f);
        }
        __syncthreads();
        const float mu = stats[0][wl], rstd = stats[1][wl];
#pragma unroll
        for (int c8 = 0; c8 < 4; c8++) {
            s16x8 pack;
#pragma unroll
            for (int j = 0; j < 8; j++) {
                int c = quad * 32 + c8 * 8 + j;
                float xn = (xv[c8 * 8 + j] - mu) * rstd * lnw[c] + lnb[c];
                pack[j] = f2bf(xn);
            }
            *(s16x8*)(&sB[wl * 136 + quad * 32 + c8 * 8]) = pack;
        }
    }
    __syncthreads();

    {
        f32x4 acc2[4][4];
#pragma unroll
        for (int i = 0; i < 4; i++)
#pragma unroll
            for (int nt = 0; nt < 4; nt++) acc2[i][nt] = (f32x4){0.f, 0.f, 0.f, 0.f};

#pragma unroll
        for (int kk = 0; kk < 4; kk++) {
            s16x8 a[4], bf[4];
#pragma unroll
            for (int i = 0; i < 4; i++)
                a[i] = *(const s16x8*)(w1_bf + (size_t)((ww * 4 + i) * 16 + lm) * 128 + kk * 32 + lq * 8);
#pragma unroll
            for (int nt = 0; nt < 4; nt++)
                bf[nt] = *(const s16x8*)(&sB[(nt * 16 + lm) * 136 + kk * 32 + lq * 8]);
#pragma unroll
            for (int i = 0; i < 4; i++)
#pragma unroll
                for (int nt = 0; nt < 4; nt++)
                    acc2[i][nt] = __builtin_amdgcn_mfma_f32_16x16x32_bf16(a[i], bf[nt], acc2[i][nt], 0, 0, 0);
        }
#pragma unroll
        for (int i = 0; i < 4; i++) {
            const int jb = ww * 64 + i * 16 + lq * 4;
            float bias[4];
#pragma unroll
            for (int r = 0; r < 4; r++) bias[r] = b1[jb + r];
#pragma unroll
            for (int nt = 0; nt < 4; nt++) {
                const int wg = nt * 16 + lm;
                s16x4 pack;
#pragma unroll
                for (int r = 0; r < 4; r++) {
                    float hv = acc2[i][nt][r] + bias[r];
                    float act = hv / (1.f + expf(-hv));
                    pack[r] = f2bf(act);
                }
                *(s16x4*)(&hb[wg * 264 + jb]) = pack;
            }
        }
    }
    __syncthreads();

    f32x4 acc3[2][4];
#pragma unroll
    for (int i = 0; i < 2; i++)
#pragma unroll
        for (int nt = 0; nt < 4; nt++) acc3[i][nt] = (f32x4){0.f, 0.f, 0.f, 0.f};

#pragma unroll
    for (int kk = 0; kk < 8; kk++) {
        s16x8 a[2], bf[4];
#pragma unroll
        for (int i = 0; i < 2; i++)
            a[i] = *(const s16x8*)(w2_bf + (size_t)((ww * 2 + i) * 16 + lm) * 256 + kk * 32 + lq * 8);
#pragma unroll
        for (int nt = 0; nt < 4; nt++)
            bf[nt] = *(const s16x8*)(&hb[(nt * 16 + lm) * 264 + kk * 32 + lq * 8]);
#pragma unroll
        for (int i = 0; i < 2; i++)
#pragma unroll
            for (int nt = 0; nt < 4; nt++)
                acc3[i][nt] = __builtin_amdgcn_mfma_f32_16x16x32_bf16(a[i], bf[nt], acc3[i][nt], 0, 0, 0);
    }

    float* outp = (b < 2) ? (out_ml + (size_t)b * CHW) : (out_mr + (size_t)(b - 2) * CHW);
#pragma unroll
    for (int i = 0; i < 2; i++) {
        const int ob = ww * 32 + i * 16 + lq * 4;
        float b2v[4];
#pragma unroll
        for (int r = 0; r < 4; r++) b2v[r] = b2[ob + r];
#pragma unroll
        for (int nt = 0; nt < 4; nt++) {
            const int wg = nt * 16 + lm;
            s16x4 xn4 = *(const s16x4*)(&sB[wg * 136 + ob]);
#pragma unroll
            for (int r = 0; r < 4; r++) {
                float y = bf2f(xn4[r]) + b2v[r] + acc3[i][nt][r];
                outp[(size_t)(ob + r) * HW + hWw + w0 + wg] = y;
            }
        }
    }
}

// ---------------------------------------------------------------------------
extern "C" void kernel_launch(void* const* d_in, const int* in_sizes, int n_in,
                              void* d_out, int out_size, void* d_ws, size_t ws_size,
                              hipStream_t stream)
{
    const float* match_l = (const float*)d_in[0];
    const float* match_r = (const float*)d_in[1];
    const float* feat_l  = (const float*)d_in[2];
    const float* feat_r  = (const float*)d_in[3];
    const float* norm_l  = (const float*)d_in[4];
    const float* norm_r  = (const float*)d_in[5];
    const float* gml     = (const float*)d_in[6];
    const float* gmr     = (const float*)d_in[7];
    const float* cap     = (const float*)d_in[8];
    const float* gap     = (const float*)d_in[9];
    const float* wv  = (const float*)d_in[10]; const float* bv  = (const float*)d_in[11];
    const float* wn  = (const float*)d_in[12]; const float* bn  = (const float*)d_in[13];
    const float* woc = (const float*)d_in[14]; const float* boc = (const float*)d_in[15];
    const float* wog = (const float*)d_in[16]; const float* bog = (const float*)d_in[17];
    const float* wa  = (const float*)d_in[18]; const float* ba  = (const float*)d_in[19];
    const float* wo  = (const float*)d_in[20]; const float* bo  = (const float*)d_in[21];
    const float* lnw = (const float*)d_in[22]; const float* lnb = (const float*)d_in[23];
    const float* w1  = (const float*)d_in[24]; const float* b1  = (const float*)d_in[25];
    const float* w2  = (const float*)d_in[26]; const float* b2  = (const float*)d_in[27];

    float* out = (float*)d_out;
    float* out_ml  = out;
    float* out_mr  = out + (size_t)2 * CHW;
    float* ckp_out = out + (size_t)4 * CHW;
    float* gkp_out = ckp_out + (size_t)B2v * Gg * Pp * HW;

    // workspace: attn f32 | bq f32 | 5x pixel/planar bf16 tensors | weights bf16
    float* ws = (float*)d_ws;
    float* attn_pl  = ws;                                         // 4*64*HW f32
    float* bq       = attn_pl + (size_t)B2v * 64 * HW;            // 128 f32
    short* q_bf     = (short*)(bq + 128);                         // 4*HW*128
    short* ctx_bf   = q_bf     + (size_t)B2v * HW * Cc;
    short* value_pl = ctx_bf   + (size_t)B2v * HW * Cc;           // planar bf16
    short* nfeat_pl = value_pl + (size_t)B2v * HW * Cc;           // planar bf16
    short* agg_bf   = nfeat_pl + (size_t)B2v * HW * Cc;           // pixel-major
    short* wbf      = agg_bf   + (size_t)B2v * HW * Cc;           // 114688
    short* wv_bf = wbf;
    short* wq_bf = wbf + 16384;
    short* wo_bf = wbf + 32768;
    short* w1_bf = wbf + 49152;
    short* w2_bf = wbf + 81920;

    dim3 blk(256);
    prep_kernel<<<dim3(449), blk, 0, stream>>>(
        wv, woc, wog, wa, wo, w1, w2, boc, bog, ba, wbf, bq);
    pack_kernel<<<dim3(4, Hh, 8), blk, 0, stream>>>(
        match_l, match_r, feat_l, feat_r, q_bf, ctx_bf);
    kv_mfma_kernel<<<dim3(4, Hh, B2v), blk, 0, stream>>>(
        ctx_bf, norm_l, norm_r, wv_bf, bv, wn, bn, value_pl, nfeat_pl);
    qp_mfma_kernel<<<dim3(4, Hh, B2v), blk, 0, stream>>>(
        q_bf, wq_bf, bq, cap, gap, attn_pl, ckp_out, gkp_out);
    samp_kernel<<<dim3(Gg, Hh, B2v), blk, 0, stream>>>(
        value_pl, nfeat_pl, attn_pl, ckp_out, gkp_out, agg_bf);
    ffn_mfma_kernel<<<dim3(4, Hh, B2v), blk, 0, stream>>>(
        agg_bf, match_l, match_r, gml, gmr, wo_bf, bo, lnw, lnb,
        w1_bf, b1, w2_bf, b2, out_ml, out_mr);
}

// Round 4
// 250.945 us; speedup vs baseline: 4.3136x; 1.1201x over previous
//
#include <hip/hip_runtime.h>
#include <cstdint>
#include <math.h>

#define B2v 4
#define Cc  128
#define Hh  64
#define Ww  256
#define Gg  8
#define Pp  4
#define HW  (Hh*Ww)      // 16384
#define CHW (Cc*HW)      // 2097152

typedef float f32x4 __attribute__((ext_vector_type(4)));
typedef short s16x8 __attribute__((ext_vector_type(8)));
typedef short s16x4 __attribute__((ext_vector_type(4)));

__device__ __forceinline__ short f2bf(float x) {
    union { float f; unsigned u; } a; a.f = x;
    unsigned r = a.u + 0x7fffu + ((a.u >> 16) & 1u);   // RNE
    return (short)(r >> 16);
}
__device__ __forceinline__ float bf2f(short s) {
    union { unsigned u; float f; } a; a.u = ((unsigned)(unsigned short)s) << 16;
    return a.f;
}
// pack two f32 into dword of two bf16 (truncation) via v_perm_b32
__device__ __forceinline__ unsigned pack2_bf(float f0, float f1) {
    union { float f; unsigned u; } a, b; a.f = f0; b.f = f1;
    // result: low short = hi16(f0), high short = hi16(f1)
    return __builtin_amdgcn_perm(b.u, a.u, 0x07060302);
}

// ---------------------------------------------------------------------------
// Kernel 0: weights f32 -> bf16. Layout in wbf:
// [0,16384) wv | [16384,32768) wq=[woc;wog;wa] | [32768,49152) wo
// [49152,81920) w1 | [81920,114688) w2 ; bq[128] = [boc;bog;ba] (f32)
// ---------------------------------------------------------------------------
__global__ __launch_bounds__(256) void prep_kernel(
    const float* __restrict__ wv, const float* __restrict__ woc,
    const float* __restrict__ wog, const float* __restrict__ wa,
    const float* __restrict__ wo, const float* __restrict__ w1,
    const float* __restrict__ w2,
    const float* __restrict__ boc, const float* __restrict__ bog,
    const float* __restrict__ ba,
    short* __restrict__ wbf, float* __restrict__ bq)
{
    int i = blockIdx.x * 256 + threadIdx.x;
    if (i < 16384) wbf[i] = f2bf(wv[i]);
    else if (i < 32768) {
        int j = i - 16384; int r = j >> 7, c = j & 127;
        float v = (r < 32) ? woc[r * 128 + c] : (r < 64) ? wog[(r - 32) * 128 + c]
                                              : wa[(r - 64) * 128 + c];
        wbf[i] = f2bf(v);
    }
    else if (i < 49152)  wbf[i] = f2bf(wo[i - 32768]);
    else if (i < 81920)  wbf[i] = f2bf(w1[i - 49152]);
    else if (i < 114688) wbf[i] = f2bf(w2[i - 81920]);
    else if (i < 114816) {
        int r = i - 114688;
        bq[r] = (r < 32) ? boc[r] : (r < 64) ? bog[r - 32] : ba[r - 64];
    }
}

// ---------------------------------------------------------------------------
// Kernel 1 (MFMA): value = wv @ ctx + bv -> planar bf16.
// In-kernel staging: planar f32 -> pixel-major bf16 tile (no pack kernel).
// ctx = concat([feat_right, feat_left])  (cross)
// ---------------------------------------------------------------------------
__global__ __launch_bounds__(256, 4) void kv_kernel(
    const float* __restrict__ fl, const float* __restrict__ fr,
    const short* __restrict__ wv_bf, const float* __restrict__ bv,
    short* __restrict__ value_pl)
{
    __shared__ short sB[64 * 136];
    const int t = threadIdx.x;
    const int lane = t & 63;
    const int ww = t >> 6;
    const int lm = lane & 15, lq = lane >> 4;
    const int wt = blockIdx.x, h = blockIdx.y, b = blockIdx.z;
    const int w0 = wt * 64;
    const int hWw = h * Ww;

    const float* src = (b < 2) ? fr + (size_t)b * CHW : fl + (size_t)(b - 2) * CHW;

    // stage: wave ww packs channels [ww*32, ww*32+32) for its 64 pixels
    {
        const int c0 = ww * 32;
        const size_t rowbase = (size_t)c0 * HW + hWw + w0 + lane;
#pragma unroll
        for (int k = 0; k < 16; k++) {
            float f0 = src[rowbase + (size_t)(2 * k) * HW];
            float f1 = src[rowbase + (size_t)(2 * k + 1) * HW];
            *(unsigned*)(&sB[lane * 136 + c0 + 2 * k]) = pack2_bf(f0, f1);
        }
    }
    __syncthreads();

    f32x4 acc[2][4];
#pragma unroll
    for (int i = 0; i < 2; i++)
#pragma unroll
        for (int nt = 0; nt < 4; nt++) acc[i][nt] = (f32x4){0.f, 0.f, 0.f, 0.f};

#pragma unroll
    for (int kk = 0; kk < 4; kk++) {
        s16x8 a[2], bf[4];
#pragma unroll
        for (int i = 0; i < 2; i++)
            a[i] = *(const s16x8*)(wv_bf + (size_t)((ww * 2 + i) * 16 + lm) * 128 + kk * 32 + lq * 8);
#pragma unroll
        for (int nt = 0; nt < 4; nt++)
            bf[nt] = *(const s16x8*)(&sB[(nt * 16 + lm) * 136 + kk * 32 + lq * 8]);
#pragma unroll
        for (int i = 0; i < 2; i++)
#pragma unroll
            for (int nt = 0; nt < 4; nt++)
                acc[i][nt] = __builtin_amdgcn_mfma_f32_16x16x32_bf16(a[i], bf[nt], acc[i][nt], 0, 0, 0);
    }

#pragma unroll
    for (int i = 0; i < 2; i++) {
        const int ob = ww * 32 + i * 16 + lq * 4;
        float bias[4];
#pragma unroll
        for (int r = 0; r < 4; r++) bias[r] = bv[ob + r];
#pragma unroll
        for (int nt = 0; nt < 4; nt++) {
            const int wg = nt * 16 + lm;
#pragma unroll
            for (int r = 0; r < 4; r++)
                value_pl[(size_t)(b * Cc + ob + r) * HW + hWw + w0 + wg] =
                    f2bf(acc[i][nt][r] + bias[r]);
        }
    }
}

// ---------------------------------------------------------------------------
// Kernel 2 (MFMA): proj = wq @ q + bq, softmax, keypoints -> d_out,
// attn -> ws. In-kernel staging; sB/sP share one LDS buffer (union).
// ---------------------------------------------------------------------------
__global__ __launch_bounds__(256, 4) void qp_kernel(
    const float* __restrict__ mlq, const float* __restrict__ mrq,
    const short* __restrict__ wq_bf, const float* __restrict__ bq,
    const float* __restrict__ cap, const float* __restrict__ gap,
    float* __restrict__ attn_pl, float* __restrict__ ckp_out, float* __restrict__ gkp_out)
{
    __shared__ float sP[128 * 64];          // 32 KB; low 17.4 KB doubles as sB
    short* const sB = (short*)sP;
    const int t = threadIdx.x;
    const int lane = t & 63;
    const int ww = t >> 6;
    const int lm = lane & 15, lq = lane >> 4;
    const int wt = blockIdx.x, h = blockIdx.y, b = blockIdx.z;
    const int w0 = wt * 64;
    const int hWw = h * Ww;

    const float* src = (b < 2) ? mlq + (size_t)b * CHW : mrq + (size_t)(b - 2) * CHW;

    {
        const int c0 = ww * 32;
        const size_t rowbase = (size_t)c0 * HW + hWw + w0 + lane;
#pragma unroll
        for (int k = 0; k < 16; k++) {
            float f0 = src[rowbase + (size_t)(2 * k) * HW];
            float f1 = src[rowbase + (size_t)(2 * k + 1) * HW];
            *(unsigned*)(&sB[lane * 136 + c0 + 2 * k]) = pack2_bf(f0, f1);
        }
    }
    __syncthreads();

    f32x4 acc[2][4];
#pragma unroll
    for (int i = 0; i < 2; i++)
#pragma unroll
        for (int nt = 0; nt < 4; nt++) acc[i][nt] = (f32x4){0.f, 0.f, 0.f, 0.f};

#pragma unroll
    for (int kk = 0; kk < 4; kk++) {
        s16x8 a[2], bf[4];
#pragma unroll
        for (int i = 0; i < 2; i++)
            a[i] = *(const s16x8*)(wq_bf + (size_t)((ww * 2 + i) * 16 + lm) * 128 + kk * 32 + lq * 8);
#pragma unroll
        for (int nt = 0; nt < 4; nt++)
            bf[nt] = *(const s16x8*)(&sB[(nt * 16 + lm) * 136 + kk * 32 + lq * 8]);
#pragma unroll
        for (int i = 0; i < 2; i++)
#pragma unroll
            for (int nt = 0; nt < 4; nt++)
                acc[i][nt] = __builtin_amdgcn_mfma_f32_16x16x32_bf16(a[i], bf[nt], acc[i][nt], 0, 0, 0);
    }
    __syncthreads();   // sB fully consumed; safe to overwrite as sP

#pragma unroll
    for (int i = 0; i < 2; i++) {
        const int ob = ww * 32 + i * 16 + lq * 4;
        float bias[4];
#pragma unroll
        for (int r = 0; r < 4; r++) bias[r] = bq[ob + r];
#pragma unroll
        for (int nt = 0; nt < 4; nt++) {
            const int wg = nt * 16 + lm;
#pragma unroll
            for (int r = 0; r < 4; r++)
                sP[(ob + r) * 64 + wg] = acc[i][nt][r] + bias[r];
        }
    }
    __syncthreads();

    for (int pi = t; pi < 512; pi += 256) {
        int g = pi >> 6;
        int w = pi & 63;
        float L[8], m = -1e30f;
#pragma unroll
        for (int j = 0; j < 8; j++) { L[j] = sP[(64 + g * 8 + j) * 64 + w]; m = fmaxf(m, L[j]); }
        float s = 0.f;
#pragma unroll
        for (int j = 0; j < 8; j++) { L[j] = expf(L[j] - m); s += L[j]; }
        float inv = 1.f / s;
#pragma unroll
        for (int j = 0; j < 8; j++)
            attn_pl[((((size_t)b * Gg + g) * 8 + j) * Hh + h) * Ww + w0 + w] = L[j] * inv;
#pragma unroll
        for (int p = 0; p < 4; p++) {
            size_t kidx = ((((size_t)b * Gg + g) * Pp + p) * Hh + h) * Ww + w0 + w;
            float oc = sP[(g * 4 + p) * 64 + w];
            float og = sP[(32 + g * 4 + p) * 64 + w];
            float ck = fminf(fmaxf(cap[kidx] * 255.0f + oc, 0.f), 255.f);
            float gk = fminf(fmaxf(gap[kidx] * 255.0f + og, 0.f), 255.f);
            ckp_out[kidx] = ck;
            gkp_out[kidx] = gk;
        }
    }
}

// ---------------------------------------------------------------------------
// Kernel 3: sampling + aggregation -> agg bf16 [b][h][w][c].
// nfeat eliminated by linearity: sample(wn@geo+bn) == wn@sample(geo)+bn.
// ---------------------------------------------------------------------------
__global__ __launch_bounds__(256) void samp_kernel(
    const short* __restrict__ value_pl,
    const float* __restrict__ nl, const float* __restrict__ nr,
    const float* __restrict__ wn, const float* __restrict__ bn,
    const float* __restrict__ attn_pl,
    const float* __restrict__ ckp, const float* __restrict__ gkp,
    short* __restrict__ agg_bf)
{
    __shared__ float vrow[Ww * 17];
    __shared__ float sgeo[3][Ww];
    __shared__ float swn[16][4];
    const int t = threadIdx.x;
    const int g = blockIdx.x, h = blockIdx.y, b = blockIdx.z;

#pragma unroll
    for (int r = 0; r < 16; r++)
        vrow[t * 17 + r] = bf2f(value_pl[(((size_t)b * Cc + g * 16 + r) * Hh + h) * Ww + t]);
    const float* geo = (b < 2) ? nr + (size_t)b * 3 * HW : nl + (size_t)(b - 2) * 3 * HW;
#pragma unroll
    for (int e = 0; e < 3; e++) sgeo[e][t] = geo[(size_t)e * HW + h * Ww + t];
    if (t < 16) {
        swn[t][0] = wn[(g * 16 + t) * 3 + 0];
        swn[t][1] = wn[(g * 16 + t) * 3 + 1];
        swn[t][2] = wn[(g * 16 + t) * 3 + 2];
        swn[t][3] = bn[g * 16 + t];
    }
    __syncthreads();

    const int w = t;
    float a8[8], kp8[8];
#pragma unroll
    for (int j = 0; j < 8; j++)
        a8[j] = attn_pl[((((size_t)b * Gg + g) * 8 + j) * Hh + h) * Ww + w];
#pragma unroll
    for (int p = 0; p < 4; p++) {
        size_t kidx = ((((size_t)b * Gg + g) * Pp + p) * Hh + h) * Ww + w;
        kp8[p]     = ckp[kidx];
        kp8[4 + p] = gkp[kidx];
    }

    float acc[16];
#pragma unroll
    for (int d = 0; d < 16; d++) acc[d] = 0.f;

    // ctx points: gather from value row
#pragma unroll
    for (int j = 0; j < 4; j++) {
        float x = kp8[j];
        int i0 = (int)floorf(x);
        int i1 = min(i0 + 1, Ww - 1);
        float tt = x - (float)i0;
        float c0 = a8[j] * (1.f - tt);
        float c1 = a8[j] * tt;
#pragma unroll
        for (int d = 0; d < 16; d++)
            acc[d] += c0 * vrow[i0 * 17 + d] + c1 * vrow[i1 * 17 + d];
    }
    // geo points: sample 3-ch geo, then apply wn rows of this group
    {
        float gs0 = 0.f, gs1 = 0.f, gs2 = 0.f, asum = 0.f;
#pragma unroll
        for (int j = 4; j < 8; j++) {
            float x = kp8[j];
            int i0 = (int)floorf(x);
            int i1 = min(i0 + 1, Ww - 1);
            float tt = x - (float)i0;
            float c0 = a8[j] * (1.f - tt);
            float c1 = a8[j] * tt;
            gs0 += c0 * sgeo[0][i0] + c1 * sgeo[0][i1];
            gs1 += c0 * sgeo[1][i0] + c1 * sgeo[1][i1];
            gs2 += c0 * sgeo[2][i0] + c1 * sgeo[2][i1];
            asum += a8[j];
        }
#pragma unroll
        for (int d = 0; d < 16; d++)
            acc[d] += swn[d][0] * gs0 + swn[d][1] * gs1 + swn[d][2] * gs2 + swn[d][3] * asum;
    }

    union { uint4 v[2]; short s[16]; } pk;
#pragma unroll
    for (int d = 0; d < 16; d++) pk.s[d] = f2bf(acc[d]);
    short* dst = agg_bf + ((size_t)((b * Hh + h) * Ww + w)) * 128 + g * 16;
    *(uint4*)(dst)     = pk.v[0];
    *(uint4*)(dst + 8) = pk.v[1];
}

// ---------------------------------------------------------------------------
// Kernel 4 (MFMA): out-proj + mask + residual + LN + FFN.
// FFN hidden j-split into two 128-col passes -> LDS 37.4 KB -> 4 blocks/CU.
// ---------------------------------------------------------------------------
__global__ __launch_bounds__(256, 3) void ffn_kernel(
    const short* __restrict__ agg_bf,
    const float* __restrict__ mlq, const float* __restrict__ mrq,
    const float* __restrict__ gml, const float* __restrict__ gmr,
    const short* __restrict__ wo_bf, const float* __restrict__ bo,
    const float* __restrict__ lnw, const float* __restrict__ lnb,
    const short* __restrict__ w1_bf, const float* __restrict__ b1,
    const short* __restrict__ w2_bf, const float* __restrict__ b2,
    float* __restrict__ out_ml, float* __restrict__ out_mr)
{
    __shared__ short sB[64 * 136];     // agg tile -> x -> xn
    __shared__ short hb[64 * 136];     // FFN hidden, 128 cols per pass
    __shared__ float red[2][4][64];
    __shared__ float stats[2][64];

    const int t    = threadIdx.x;
    const int lane = t & 63;
    const int ww   = t >> 6;
    const int lm   = lane & 15;
    const int lq   = lane >> 4;
    const int wt = blockIdx.x, h = blockIdx.y, b = blockIdx.z;
    const int w0 = wt * 64;
    const int hWw = h * Ww;

    const uint4* gsrc = (const uint4*)(agg_bf + ((size_t)((b * Hh + h) * Ww + w0)) * 128);
#pragma unroll
    for (int i = 0; i < 4; i++) {
        int chunk = i * 256 + t;
        int w = chunk >> 4, cc = chunk & 15;
        uint4 v = gsrc[chunk];
        *(uint4*)(&sB[w * 136 + cc * 8]) = v;
    }
    __syncthreads();

    // GEMM1: upd = wo @ agg
    f32x4 acc1[2][4];
#pragma unroll
    for (int i = 0; i < 2; i++)
#pragma unroll
        for (int nt = 0; nt < 4; nt++) acc1[i][nt] = (f32x4){0.f, 0.f, 0.f, 0.f};

#pragma unroll
    for (int kk = 0; kk < 4; kk++) {
        s16x8 a[2], bf[4];
#pragma unroll
        for (int i = 0; i < 2; i++)
            a[i] = *(const s16x8*)(wo_bf + (size_t)((ww * 2 + i) * 16 + lm) * 128 + kk * 32 + lq * 8);
#pragma unroll
        for (int nt = 0; nt < 4; nt++)
            bf[nt] = *(const s16x8*)(&sB[(nt * 16 + lm) * 136 + kk * 32 + lq * 8]);
#pragma unroll
        for (int i = 0; i < 2; i++)
#pragma unroll
            for (int nt = 0; nt < 4; nt++)
                acc1[i][nt] = __builtin_amdgcn_mfma_f32_16x16x32_bf16(a[i], bf[nt], acc1[i][nt], 0, 0, 0);
    }
    __syncthreads();

    // x = q + (upd + bo) * mask -> sB
    const float* msk = (b < 2) ? (gml + (size_t)b * HW) : (gmr + (size_t)(b - 2) * HW);
    const float* q   = (b < 2) ? (mlq + (size_t)b * CHW) : (mrq + (size_t)(b - 2) * CHW);
    float mvals[4];
#pragma unroll
    for (int nt = 0; nt < 4; nt++) mvals[nt] = msk[hWw + w0 + nt * 16 + lm];

#pragma unroll
    for (int i = 0; i < 2; i++) {
        const int ob = ww * 32 + i * 16 + lq * 4;
        float bias[4];
#pragma unroll
        for (int r = 0; r < 4; r++) bias[r] = bo[ob + r];
#pragma unroll
        for (int nt = 0; nt < 4; nt++) {
            const int wg = nt * 16 + lm;
            s16x4 pack;
#pragma unroll
            for (int r = 0; r < 4; r++) {
                float upd = acc1[i][nt][r] + bias[r];
                float qv = q[(size_t)(ob + r) * HW + hWw + w0 + wg];
                float x = qv + upd * mvals[nt];
                pack[r] = f2bf(x);
            }
            *(s16x4*)(&sB[wg * 136 + ob]) = pack;
        }
    }
    __syncthreads();

    // LayerNorm over channels
    {
        const int quad = ww, wl = lane;
        float xv[32];
#pragma unroll
        for (int c8 = 0; c8 < 4; c8++) {
            s16x8 v = *(const s16x8*)(&sB[wl * 136 + quad * 32 + c8 * 8]);
#pragma unroll
            for (int j = 0; j < 8; j++) xv[c8 * 8 + j] = bf2f(v[j]);
        }
        float lsum = 0.f, lsq = 0.f;
#pragma unroll
        for (int k = 0; k < 32; k++) { lsum += xv[k]; lsq += xv[k] * xv[k]; }
        red[0][quad][wl] = lsum;
        red[1][quad][wl] = lsq;
        __syncthreads();
        if (t < 64) {
            float s  = red[0][0][wl] + red[0][1][wl] + red[0][2][wl] + red[0][3][wl];
            float ss = red[1][0][wl] + red[1][1][wl] + red[1][2][wl] + red[1][3][wl];
            float mu = s * (1.f / 128.f);
            float var = ss * (1.f / 128.f) - mu * mu;
            stats[0][wl] = mu;
            stats[1][wl] = rsqrtf(var + 1e-5f);
        }
        __syncthreads();
        const float mu = stats[0][wl], rstd = stats[1][wl];
#pragma unroll
        for (int c8 = 0; c8 < 4; c8++) {
            s16x8 pack;
#pragma unroll
            for (int j = 0; j < 8; j++) {
                int c = quad * 32 + c8 * 8 + j;
                float xn = (xv[c8 * 8 + j] - mu) * rstd * lnw[c] + lnb[c];
                pack[j] = f2bf(xn);
            }
            *(s16x8*)(&sB[wl * 136 + quad * 32 + c8 * 8]) = pack;
        }
    }
    __syncthreads();

    // FFN: two passes of 128 hidden cols; acc3 accumulates across passes
    f32x4 acc3[2][4];
#pragma unroll
    for (int i = 0; i < 2; i++)
#pragma unroll
        for (int nt = 0; nt < 4; nt++) acc3[i][nt] = (f32x4){0.f, 0.f, 0.f, 0.f};

    for (int jc = 0; jc < 2; jc++) {
        // GEMM2: h = silu(w1[jc*128 + 0..128) @ xn + b1)
        f32x4 acc2[2][4];
#pragma unroll
        for (int i = 0; i < 2; i++)
#pragma unroll
            for (int nt = 0; nt < 4; nt++) acc2[i][nt] = (f32x4){0.f, 0.f, 0.f, 0.f};

#pragma unroll
        for (int kk = 0; kk < 4; kk++) {
            s16x8 a[2], bf[4];
#pragma unroll
            for (int i = 0; i < 2; i++)
                a[i] = *(const s16x8*)(w1_bf + (size_t)(jc * 128 + ww * 32 + i * 16 + lm) * 128 + kk * 32 + lq * 8);
#pragma unroll
            for (int nt = 0; nt < 4; nt++)
                bf[nt] = *(const s16x8*)(&sB[(nt * 16 + lm) * 136 + kk * 32 + lq * 8]);
#pragma unroll
            for (int i = 0; i < 2; i++)
#pragma unroll
                for (int nt = 0; nt < 4; nt++)
                    acc2[i][nt] = __builtin_amdgcn_mfma_f32_16x16x32_bf16(a[i], bf[nt], acc2[i][nt], 0, 0, 0);
        }
#pragma unroll
        for (int i = 0; i < 2; i++) {
            const int jb = ww * 32 + i * 16 + lq * 4;       // local col in [0,128)
            float bias[4];
#pragma unroll
            for (int r = 0; r < 4; r++) bias[r] = b1[jc * 128 + jb + r];
#pragma unroll
            for (int nt = 0; nt < 4; nt++) {
                const int wg = nt * 16 + lm;
                s16x4 pack;
#pragma unroll
                for (int r = 0; r < 4; r++) {
                    float hv = acc2[i][nt][r] + bias[r];
                    pack[r] = f2bf(hv / (1.f + expf(-hv)));
                }
                *(s16x4*)(&hb[wg * 136 + jb]) = pack;
            }
        }
        __syncthreads();

        // GEMM3 partial: acc3 += w2[:, jc*128 + 0..128) @ act
#pragma unroll
        for (int kk = 0; kk < 4; kk++) {
            s16x8 a[2], bf[4];
#pragma unroll
            for (int i = 0; i < 2; i++)
                a[i] = *(const s16x8*)(w2_bf + (size_t)((ww * 2 + i) * 16 + lm) * 256 + jc * 128 + kk * 32 + lq * 8);
#pragma unroll
            for (int nt = 0; nt < 4; nt++)
                bf[nt] = *(const s16x8*)(&hb[(nt * 16 + lm) * 136 + kk * 32 + lq * 8]);
#pragma unroll
            for (int i = 0; i < 2; i++)
#pragma unroll
                for (int nt = 0; nt < 4; nt++)
                    acc3[i][nt] = __builtin_amdgcn_mfma_f32_16x16x32_bf16(a[i], bf[nt], acc3[i][nt], 0, 0, 0);
        }
        __syncthreads();
    }

    float* outp = (b < 2) ? (out_ml + (size_t)b * CHW) : (out_mr + (size_t)(b - 2) * CHW);
#pragma unroll
    for (int i = 0; i < 2; i++) {
        const int ob = ww * 32 + i * 16 + lq * 4;
        float b2v[4];
#pragma unroll
        for (int r = 0; r < 4; r++) b2v[r] = b2[ob + r];
#pragma unroll
        for (int nt = 0; nt < 4; nt++) {
            const int wg = nt * 16 + lm;
            s16x4 xn4 = *(const s16x4*)(&sB[wg * 136 + ob]);
#pragma unroll
            for (int r = 0; r < 4; r++) {
                float y = bf2f(xn4[r]) + b2v[r] + acc3[i][nt][r];
                outp[(size_t)(ob + r) * HW + hWw + w0 + wg] = y;
            }
        }
    }
}

// ---------------------------------------------------------------------------
extern "C" void kernel_launch(void* const* d_in, const int* in_sizes, int n_in,
                              void* d_out, int out_size, void* d_ws, size_t ws_size,
                              hipStream_t stream)
{
    const float* match_l = (const float*)d_in[0];
    const float* match_r = (const float*)d_in[1];
    const float* feat_l  = (const float*)d_in[2];
    const float* feat_r  = (const float*)d_in[3];
    const float* norm_l  = (const float*)d_in[4];
    const float* norm_r  = (const float*)d_in[5];
    const float* gml     = (const float*)d_in[6];
    const float* gmr     = (const float*)d_in[7];
    const float* cap     = (const float*)d_in[8];
    const float* gap     = (const float*)d_in[9];
    const float* wv  = (const float*)d_in[10]; const float* bv  = (const float*)d_in[11];
    const float* wn  = (const float*)d_in[12]; const float* bn  = (const float*)d_in[13];
    const float* woc = (const float*)d_in[14]; const float* boc = (const float*)d_in[15];
    const float* wog = (const float*)d_in[16]; const float* bog = (const float*)d_in[17];
    const float* wa  = (const float*)d_in[18]; const float* ba  = (const float*)d_in[19];
    const float* wo  = (const float*)d_in[20]; const float* bo  = (const float*)d_in[21];
    const float* lnw = (const float*)d_in[22]; const float* lnb = (const float*)d_in[23];
    const float* w1  = (const float*)d_in[24]; const float* b1  = (const float*)d_in[25];
    const float* w2  = (const float*)d_in[26]; const float* b2  = (const float*)d_in[27];

    float* out = (float*)d_out;
    float* out_ml  = out;
    float* out_mr  = out + (size_t)2 * CHW;
    float* ckp_out = out + (size_t)4 * CHW;
    float* gkp_out = ckp_out + (size_t)B2v * Gg * Pp * HW;

    float* ws = (float*)d_ws;
    float* attn_pl  = ws;                                       // 4*64*HW f32
    float* bq       = attn_pl + (size_t)B2v * 64 * HW;          // 128 f32
    short* value_pl = (short*)(bq + 128);                       // 4*128*HW bf16 planar
    short* agg_bf   = value_pl + (size_t)B2v * Cc * HW;         // 4*HW*128 bf16 pixel-major
    short* wbf      = agg_bf   + (size_t)B2v * HW * Cc;         // 114688 bf16
    short* wv_bf = wbf;
    short* wq_bf = wbf + 16384;
    short* wo_bf = wbf + 32768;
    short* w1_bf = wbf + 49152;
    short* w2_bf = wbf + 81920;

    dim3 blk(256);
    prep_kernel<<<dim3(449), blk, 0, stream>>>(
        wv, woc, wog, wa, wo, w1, w2, boc, bog, ba, wbf, bq);
    kv_kernel<<<dim3(4, Hh, B2v), blk, 0, stream>>>(
        feat_l, feat_r, wv_bf, bv, value_pl);
    qp_kernel<<<dim3(4, Hh, B2v), blk, 0, stream>>>(
        match_l, match_r, wq_bf, bq, cap, gap, attn_pl, ckp_out, gkp_out);
    samp_kernel<<<dim3(Gg, Hh, B2v), blk, 0, stream>>>(
        value_pl, norm_l, norm_r, wn, bn, attn_pl, ckp_out, gkp_out, agg_bf);
    ffn_kernel<<<dim3(4, Hh, B2v), blk, 0, stream>>>(
        agg_bf, match_l, match_r, gml, gmr, wo_bf, bo, lnw, lnb,
        w1_bf, b1, w2_bf, b2, out_ml, out_mr);
}

// Round 5
// 222.311 us; speedup vs baseline: 4.8692x; 1.1288x over previous
//
#include <hip/hip_runtime.h>
#include <cstdint>
#include <math.h>

#define B2v 4
#define Cc  128
#define Hh  64
#define Ww  256
#define Gg  8
#define Pp  4
#define HW  (Hh*Ww)      // 16384
#define CHW (Cc*HW)      // 2097152
#define PIT 136          // LDS tile pitch in bf16 elems (272 B, 16B-aligned rows)

typedef float f32x4 __attribute__((ext_vector_type(4)));
typedef short s16x8 __attribute__((ext_vector_type(8)));
typedef short s16x4 __attribute__((ext_vector_type(4)));

__device__ __forceinline__ short f2bf(float x) {
    union { float f; unsigned u; } a; a.f = x;
    unsigned r = a.u + 0x7fffu + ((a.u >> 16) & 1u);   // RNE
    return (short)(r >> 16);
}
__device__ __forceinline__ float bf2f(short s) {
    union { unsigned u; float f; } a; a.u = ((unsigned)(unsigned short)s) << 16;
    return a.f;
}
__device__ __forceinline__ unsigned pack2_bf(float f0, float f1) {
    union { float f; unsigned u; } a, b; a.f = f0; b.f = f1;
    return __builtin_amdgcn_perm(b.u, a.u, 0x07060302);  // lo=hi16(f0), hi=hi16(f1)
}

// ---------------------------------------------------------------------------
// Kernel 0: weights f32 -> bf16.
// [0,16384) wv | [16384,32768) wq=[woc;wog;wa] | [32768,49152) wo
// [49152,81920) w1 | [81920,114688) w2 ; bq[128]=[boc;bog;ba] f32
// ---------------------------------------------------------------------------
__global__ __launch_bounds__(256) void prep_kernel(
    const float* __restrict__ wv, const float* __restrict__ woc,
    const float* __restrict__ wog, const float* __restrict__ wa,
    const float* __restrict__ wo, const float* __restrict__ w1,
    const float* __restrict__ w2,
    const float* __restrict__ boc, const float* __restrict__ bog,
    const float* __restrict__ ba,
    short* __restrict__ wbf, float* __restrict__ bq)
{
    int i = blockIdx.x * 256 + threadIdx.x;
    if (i < 16384) wbf[i] = f2bf(wv[i]);
    else if (i < 32768) {
        int j = i - 16384; int r = j >> 7, c = j & 127;
        float v = (r < 32) ? woc[r * 128 + c] : (r < 64) ? wog[(r - 32) * 128 + c]
                                              : wa[(r - 64) * 128 + c];
        wbf[i] = f2bf(v);
    }
    else if (i < 49152)  wbf[i] = f2bf(wo[i - 32768]);
    else if (i < 81920)  wbf[i] = f2bf(w1[i - 49152]);
    else if (i < 114688) wbf[i] = f2bf(w2[i - 81920]);
    else if (i < 114816) {
        int r = i - 114688;
        bq[r] = (r < 32) ? boc[r] : (r < 64) ? bog[r - 32] : ba[r - 64];
    }
}

// ---------------------------------------------------------------------------
// Mega kernel: whole block per output row (b,h). 512 threads (8 waves).
// Phases: stage ctx -> value GEMM -> stage q -> qp GEMM -> softmax/keypoints
// (regs) -> deformable sampling -> out-proj + residual + LN -> FFN -> store.
// LDS: buf1/buf2 [256][136] bf16 ping-pong (69.6 KB each), total ~147 KB.
// ---------------------------------------------------------------------------
__global__ __launch_bounds__(512, 2) void mega_kernel(
    const float* __restrict__ mlq, const float* __restrict__ mrq,
    const float* __restrict__ fl,  const float* __restrict__ fr,
    const float* __restrict__ nl,  const float* __restrict__ nr,
    const float* __restrict__ gml, const float* __restrict__ gmr,
    const float* __restrict__ cap, const float* __restrict__ gap,
    const short* __restrict__ wbf, const float* __restrict__ bq,
    const float* __restrict__ bv,
    const float* __restrict__ wn,  const float* __restrict__ bn,
    const float* __restrict__ bo,
    const float* __restrict__ lnw, const float* __restrict__ lnb,
    const float* __restrict__ b1,  const float* __restrict__ b2,
    float* __restrict__ out_ml, float* __restrict__ out_mr,
    float* __restrict__ ckp_out, float* __restrict__ gkp_out)
{
    __shared__ short buf1[256 * PIT];   // ctx -> q -> proj -> agg/x/xn
    __shared__ short buf2[256 * PIT];   // value -> ffn hidden
    __shared__ float sgeo[3 * 256];
    __shared__ float swn4[128 * 4];
    __shared__ float redS[512], redQ[512];
    __shared__ float smu[256], srs[256];

    const short* wv_bf = wbf;
    const short* wq_bf = wbf + 16384;
    const short* wo_bf = wbf + 32768;
    const short* w1_bf = wbf + 49152;
    const short* w2_bf = wbf + 81920;

    const int t    = threadIdx.x;
    const int lane = t & 63;
    const int ww   = t >> 6;          // wave 0..7
    const int lm   = lane & 15;
    const int lq   = lane >> 4;
    const int h = blockIdx.x, b = blockIdx.y;
    const int hWw = h * Ww;
    const int px   = t & 255;         // per-pixel phases
    const int half = t >> 8;          // 0/1 (channel/group half)

    const float* ctx = (b < 2) ? fr + (size_t)b * CHW : fl + (size_t)(b - 2) * CHW;
    const float* q   = (b < 2) ? mlq + (size_t)b * CHW : mrq + (size_t)(b - 2) * CHW;
    const float* geo = (b < 2) ? nr + (size_t)b * 3 * HW : nl + (size_t)(b - 2) * 3 * HW;
    const float* msk = (b < 2) ? gml + (size_t)b * HW : gmr + (size_t)(b - 2) * HW;
    float* outp = (b < 2) ? out_ml + (size_t)b * CHW : out_mr + (size_t)(b - 2) * CHW;

    // phase 0: small constants (consumed after later barriers)
    for (int i = t; i < 768; i += 512) sgeo[i] = geo[(size_t)(i >> 8) * HW + hWw + (i & 255)];
    if (t < 128) {
        swn4[t * 4 + 0] = wn[t * 3 + 0];
        swn4[t * 4 + 1] = wn[t * 3 + 1];
        swn4[t * 4 + 2] = wn[t * 3 + 2];
        swn4[t * 4 + 3] = bn[t];
    }

    // ---- phase A: stage ctx row (planar f32 -> buf1 [px][ch] bf16) ----
    {
        const int c0 = ww * 16;
#pragma unroll
        for (int sub = 0; sub < 4; sub++) {
            const int p = sub * 64 + lane;
            const size_t base = (size_t)c0 * HW + hWw + p;
#pragma unroll
            for (int k = 0; k < 8; k++) {
                float f0 = ctx[base + (size_t)(2 * k) * HW];
                float f1 = ctx[base + (size_t)(2 * k + 1) * HW];
                *(unsigned*)(&buf1[p * PIT + c0 + 2 * k]) = pack2_bf(f0, f1);
            }
        }
    }
    __syncthreads();

    // ---- phase A2: value = wv @ ctx + bv -> buf2 [px][ch] bf16 ----
    {
        f32x4 acc[16];
#pragma unroll
        for (int nt = 0; nt < 16; nt++) acc[nt] = (f32x4){0.f, 0.f, 0.f, 0.f};
#pragma unroll
        for (int kk = 0; kk < 4; kk++) {
            s16x8 a = *(const s16x8*)(wv_bf + (size_t)(ww * 16 + lm) * 128 + kk * 32 + lq * 8);
#pragma unroll
            for (int nt = 0; nt < 16; nt++) {
                s16x8 bfv = *(const s16x8*)(&buf1[(nt * 16 + lm) * PIT + kk * 32 + lq * 8]);
                acc[nt] = __builtin_amdgcn_mfma_f32_16x16x32_bf16(a, bfv, acc[nt], 0, 0, 0);
            }
        }
        const int ob = ww * 16 + lq * 4;
        float bias[4];
#pragma unroll
        for (int r = 0; r < 4; r++) bias[r] = bv[ob + r];
#pragma unroll
        for (int nt = 0; nt < 16; nt++) {
            const int wg = nt * 16 + lm;
            s16x4 pk;
#pragma unroll
            for (int r = 0; r < 4; r++) pk[r] = f2bf(acc[nt][r] + bias[r]);
            *(s16x4*)(&buf2[wg * PIT + ob]) = pk;
        }
    }
    __syncthreads();

    // ---- phase B: stage q row -> buf1 ----
    {
        const int c0 = ww * 16;
#pragma unroll
        for (int sub = 0; sub < 4; sub++) {
            const int p = sub * 64 + lane;
            const size_t base = (size_t)c0 * HW + hWw + p;
#pragma unroll
            for (int k = 0; k < 8; k++) {
                float f0 = q[base + (size_t)(2 * k) * HW];
                float f1 = q[base + (size_t)(2 * k + 1) * HW];
                *(unsigned*)(&buf1[p * PIT + c0 + 2 * k]) = pack2_bf(f0, f1);
            }
        }
    }
    __syncthreads();

    // ---- phase B2: proj = wq @ q + bq ; write proj bf16 -> buf1 [px][row] ----
    {
        f32x4 acc[16];
#pragma unroll
        for (int nt = 0; nt < 16; nt++) acc[nt] = (f32x4){0.f, 0.f, 0.f, 0.f};
#pragma unroll
        for (int kk = 0; kk < 4; kk++) {
            s16x8 a = *(const s16x8*)(wq_bf + (size_t)(ww * 16 + lm) * 128 + kk * 32 + lq * 8);
#pragma unroll
            for (int nt = 0; nt < 16; nt++) {
                s16x8 bfv = *(const s16x8*)(&buf1[(nt * 16 + lm) * PIT + kk * 32 + lq * 8]);
                acc[nt] = __builtin_amdgcn_mfma_f32_16x16x32_bf16(a, bfv, acc[nt], 0, 0, 0);
            }
        }
        __syncthreads();   // all q reads done; overwrite buf1 with proj
        const int ob = ww * 16 + lq * 4;
        float bias[4];
#pragma unroll
        for (int r = 0; r < 4; r++) bias[r] = bq[ob + r];
#pragma unroll
        for (int nt = 0; nt < 16; nt++) {
            const int wg = nt * 16 + lm;
            s16x4 pk;
#pragma unroll
            for (int r = 0; r < 4; r++) pk[r] = f2bf(acc[nt][r] + bias[r]);
            *(s16x4*)(&buf1[wg * PIT + ob]) = pk;
        }
    }
    __syncthreads();

    // ---- phase B3: softmax + keypoints, kept in REGISTERS ----
    float attnr[4][8], kpr[4][8];
#pragma unroll
    for (int gi = 0; gi < 4; gi++) {
        const int g = half * 4 + gi;
        s16x8 lg = *(const s16x8*)(&buf1[px * PIT + 64 + g * 8]);
        float L[8], m = -1e30f;
#pragma unroll
        for (int j = 0; j < 8; j++) { L[j] = bf2f(lg[j]); m = fmaxf(m, L[j]); }
        float s = 0.f;
#pragma unroll
        for (int j = 0; j < 8; j++) { L[j] = expf(L[j] - m); s += L[j]; }
        float inv = 1.f / s;
#pragma unroll
        for (int j = 0; j < 8; j++) attnr[gi][j] = L[j] * inv;
#pragma unroll
        for (int p = 0; p < 4; p++) {
            size_t kidx = ((((size_t)b * Gg + g) * Pp + p) * Hh + h) * Ww + px;
            float oc = bf2f(buf1[px * PIT + g * 4 + p]);
            float og = bf2f(buf1[px * PIT + 32 + g * 4 + p]);
            float ck = fminf(fmaxf(cap[kidx] * 255.0f + oc, 0.f), 255.f);
            float gk = fminf(fmaxf(gap[kidx] * 255.0f + og, 0.f), 255.f);
            ckp_out[kidx] = ck;
            gkp_out[kidx] = gk;
            kpr[gi][p] = ck;
            kpr[gi][4 + p] = gk;
        }
    }
    __syncthreads();   // all proj reads done; buf1 reusable for agg

    // ---- phase C: deformable sampling -> agg bf16 in buf1 [px][ch] ----
#pragma unroll
    for (int gi = 0; gi < 4; gi++) {
        const int g = half * 4 + gi;
        float a16[16];
#pragma unroll
        for (int d = 0; d < 16; d++) a16[d] = 0.f;
        // ctx points: gather value from buf2
#pragma unroll
        for (int j = 0; j < 4; j++) {
            float x = kpr[gi][j];
            int i0 = (int)floorf(x);
            int i1 = min(i0 + 1, Ww - 1);
            float tt = x - (float)i0;
            float c0 = attnr[gi][j] * (1.f - tt);
            float c1 = attnr[gi][j] * tt;
            s16x8 v0a = *(const s16x8*)(&buf2[i0 * PIT + g * 16]);
            s16x8 v0b = *(const s16x8*)(&buf2[i0 * PIT + g * 16 + 8]);
            s16x8 v1a = *(const s16x8*)(&buf2[i1 * PIT + g * 16]);
            s16x8 v1b = *(const s16x8*)(&buf2[i1 * PIT + g * 16 + 8]);
#pragma unroll
            for (int d = 0; d < 8; d++) {
                a16[d]     += c0 * bf2f(v0a[d]) + c1 * bf2f(v1a[d]);
                a16[8 + d] += c0 * bf2f(v0b[d]) + c1 * bf2f(v1b[d]);
            }
        }
        // geo points via linearity: wn @ sample(geo) + bn * sum(attn_geo)
        {
            float gs0 = 0.f, gs1 = 0.f, gs2 = 0.f, as = 0.f;
#pragma unroll
            for (int j = 4; j < 8; j++) {
                float x = kpr[gi][j];
                int i0 = (int)floorf(x);
                int i1 = min(i0 + 1, Ww - 1);
                float tt = x - (float)i0;
                float c0 = attnr[gi][j] * (1.f - tt);
                float c1 = attnr[gi][j] * tt;
                gs0 += c0 * sgeo[i0] + c1 * sgeo[i1];
                gs1 += c0 * sgeo[256 + i0] + c1 * sgeo[256 + i1];
                gs2 += c0 * sgeo[512 + i0] + c1 * sgeo[512 + i1];
                as  += attnr[gi][j];
            }
#pragma unroll
            for (int d = 0; d < 16; d++) {
                const float* w4 = &swn4[(g * 16 + d) * 4];
                a16[d] += w4[0] * gs0 + w4[1] * gs1 + w4[2] * gs2 + w4[3] * as;
            }
        }
        s16x8 p0, p1;
#pragma unroll
        for (int d = 0; d < 8; d++) { p0[d] = f2bf(a16[d]); p1[d] = f2bf(a16[8 + d]); }
        *(s16x8*)(&buf1[px * PIT + g * 16])     = p0;
        *(s16x8*)(&buf1[px * PIT + g * 16 + 8]) = p1;
    }
    __syncthreads();

    // ---- phase F1: upd = wo @ agg ; x = q + (upd+bo)*mask -> buf1 ----
    {
        f32x4 acc1[16];
#pragma unroll
        for (int nt = 0; nt < 16; nt++) acc1[nt] = (f32x4){0.f, 0.f, 0.f, 0.f};
#pragma unroll
        for (int kk = 0; kk < 4; kk++) {
            s16x8 a = *(const s16x8*)(wo_bf + (size_t)(ww * 16 + lm) * 128 + kk * 32 + lq * 8);
#pragma unroll
            for (int nt = 0; nt < 16; nt++) {
                s16x8 bfv = *(const s16x8*)(&buf1[(nt * 16 + lm) * PIT + kk * 32 + lq * 8]);
                acc1[nt] = __builtin_amdgcn_mfma_f32_16x16x32_bf16(a, bfv, acc1[nt], 0, 0, 0);
            }
        }
        __syncthreads();   // agg reads done before in-place x write
        const int ob = ww * 16 + lq * 4;
        float bias[4];
#pragma unroll
        for (int r = 0; r < 4; r++) bias[r] = bo[ob + r];
#pragma unroll
        for (int nt = 0; nt < 16; nt++) {
            const int wg = nt * 16 + lm;
            float mval = msk[hWw + wg];
            s16x4 pk;
#pragma unroll
            for (int r = 0; r < 4; r++) {
                float upd = acc1[nt][r] + bias[r];
                float qv = q[(size_t)(ob + r) * HW + hWw + wg];
                pk[r] = f2bf(qv + upd * mval);
            }
            *(s16x4*)(&buf1[wg * PIT + ob]) = pk;
        }
    }
    __syncthreads();

    // ---- phase F2: LayerNorm over channels (in place, bf16) ----
    {
        float ls = 0.f, lsq = 0.f;
#pragma unroll
        for (int c8 = 0; c8 < 8; c8++) {
            s16x8 v = *(const s16x8*)(&buf1[px * PIT + half * 64 + c8 * 8]);
#pragma unroll
            for (int j = 0; j < 8; j++) { float f = bf2f(v[j]); ls += f; lsq += f * f; }
        }
        redS[t] = ls; redQ[t] = lsq;
        __syncthreads();
        if (t < 256) {
            float s  = redS[t] + redS[t + 256];
            float qq = redQ[t] + redQ[t + 256];
            float mu = s * (1.f / 128.f);
            float var = qq * (1.f / 128.f) - mu * mu;
            smu[t] = mu;
            srs[t] = rsqrtf(var + 1e-5f);
        }
        __syncthreads();
        const float mu = smu[px], rs = srs[px];
#pragma unroll
        for (int c8 = 0; c8 < 8; c8++) {
            s16x8 v = *(const s16x8*)(&buf1[px * PIT + half * 64 + c8 * 8]);
            s16x8 pk;
#pragma unroll
            for (int j = 0; j < 8; j++) {
                int c = half * 64 + c8 * 8 + j;
                pk[j] = f2bf((bf2f(v[j]) - mu) * rs * lnw[c] + lnb[c]);
            }
            *(s16x8*)(&buf1[px * PIT + half * 64 + c8 * 8]) = pk;
        }
    }
    __syncthreads();

    // ---- phase F3: FFN, two 128-col hidden passes; acc3 accumulates ----
    f32x4 acc3[16];
#pragma unroll
    for (int nt = 0; nt < 16; nt++) acc3[nt] = (f32x4){0.f, 0.f, 0.f, 0.f};

    for (int jc = 0; jc < 2; jc++) {
        f32x4 acc2[16];
#pragma unroll
        for (int nt = 0; nt < 16; nt++) acc2[nt] = (f32x4){0.f, 0.f, 0.f, 0.f};
#pragma unroll
        for (int kk = 0; kk < 4; kk++) {
            s16x8 a = *(const s16x8*)(w1_bf + (size_t)(jc * 128 + ww * 16 + lm) * 128 + kk * 32 + lq * 8);
#pragma unroll
            for (int nt = 0; nt < 16; nt++) {
                s16x8 bfv = *(const s16x8*)(&buf1[(nt * 16 + lm) * PIT + kk * 32 + lq * 8]);
                acc2[nt] = __builtin_amdgcn_mfma_f32_16x16x32_bf16(a, bfv, acc2[nt], 0, 0, 0);
            }
        }
        {
            const int jb = ww * 16 + lq * 4;
            float bias[4];
#pragma unroll
            for (int r = 0; r < 4; r++) bias[r] = b1[jc * 128 + jb + r];
#pragma unroll
            for (int nt = 0; nt < 16; nt++) {
                const int wg = nt * 16 + lm;
                s16x4 pk;
#pragma unroll
                for (int r = 0; r < 4; r++) {
                    float hv = acc2[nt][r] + bias[r];
                    pk[r] = f2bf(hv / (1.f + expf(-hv)));
                }
                *(s16x4*)(&buf2[wg * PIT + jb]) = pk;
            }
        }
        __syncthreads();
#pragma unroll
        for (int kk = 0; kk < 4; kk++) {
            s16x8 a = *(const s16x8*)(w2_bf + (size_t)(ww * 16 + lm) * 256 + jc * 128 + kk * 32 + lq * 8);
#pragma unroll
            for (int nt = 0; nt < 16; nt++) {
                s16x8 bfv = *(const s16x8*)(&buf2[(nt * 16 + lm) * PIT + kk * 32 + lq * 8]);
                acc3[nt] = __builtin_amdgcn_mfma_f32_16x16x32_bf16(a, bfv, acc3[nt], 0, 0, 0);
            }
        }
        __syncthreads();
    }

    // ---- store: y = xn + b2 + ffn ----
    {
        const int ob = ww * 16 + lq * 4;
        float b2v[4];
#pragma unroll
        for (int r = 0; r < 4; r++) b2v[r] = b2[ob + r];
#pragma unroll
        for (int nt = 0; nt < 16; nt++) {
            const int wg = nt * 16 + lm;
            s16x4 xn4 = *(const s16x4*)(&buf1[wg * PIT + ob]);
#pragma unroll
            for (int r = 0; r < 4; r++)
                outp[(size_t)(ob + r) * HW + hWw + wg] = bf2f(xn4[r]) + b2v[r] + acc3[nt][r];
        }
    }
}

// ---------------------------------------------------------------------------
extern "C" void kernel_launch(void* const* d_in, const int* in_sizes, int n_in,
                              void* d_out, int out_size, void* d_ws, size_t ws_size,
                              hipStream_t stream)
{
    const float* match_l = (const float*)d_in[0];
    const float* match_r = (const float*)d_in[1];
    const float* feat_l  = (const float*)d_in[2];
    const float* feat_r  = (const float*)d_in[3];
    const float* norm_l  = (const float*)d_in[4];
    const float* norm_r  = (const float*)d_in[5];
    const float* gml     = (const float*)d_in[6];
    const float* gmr     = (const float*)d_in[7];
    const float* cap     = (const float*)d_in[8];
    const float* gap     = (const float*)d_in[9];
    const float* wv  = (const float*)d_in[10]; const float* bv  = (const float*)d_in[11];
    const float* wn  = (const float*)d_in[12]; const float* bn  = (const float*)d_in[13];
    const float* woc = (const float*)d_in[14]; const float* boc = (const float*)d_in[15];
    const float* wog = (const float*)d_in[16]; const float* bog = (const float*)d_in[17];
    const float* wa  = (const float*)d_in[18]; const float* ba  = (const float*)d_in[19];
    const float* wo  = (const float*)d_in[20]; const float* bo  = (const float*)d_in[21];
    const float* lnw = (const float*)d_in[22]; const float* lnb = (const float*)d_in[23];
    const float* w1  = (const float*)d_in[24]; const float* b1  = (const float*)d_in[25];
    const float* w2  = (const float*)d_in[26]; const float* b2  = (const float*)d_in[27];

    float* out = (float*)d_out;
    float* out_ml  = out;
    float* out_mr  = out + (size_t)2 * CHW;
    float* ckp_out = out + (size_t)4 * CHW;
    float* gkp_out = ckp_out + (size_t)B2v * Gg * Pp * HW;

    float* ws = (float*)d_ws;
    float* bq  = ws;                       // 128 f32
    short* wbf = (short*)(bq + 128);       // 114688 bf16

    prep_kernel<<<dim3(449), dim3(256), 0, stream>>>(
        wv, woc, wog, wa, wo, w1, w2, boc, bog, ba, wbf, bq);
    mega_kernel<<<dim3(Hh, B2v), dim3(512), 0, stream>>>(
        match_l, match_r, feat_l, feat_r, norm_l, norm_r, gml, gmr, cap, gap,
        wbf, bq, bv, wn, bn, bo, lnw, lnb, b1, b2,
        out_ml, out_mr, ckp_out, gkp_out);
}